// Round 9
// baseline (427.550 us; speedup 1.0000x reference)
//
#include <hip/hip_runtime.h>
#include <hip/hip_fp16.h>
#include <math.h>

#define N_NODES 100000
#define N_EDGES 1000000
#define IN_DIM 64
#define HID 64
#define NC 30
#define NCP 32              // padded row width for fp16 feature rows (64 B)
#define REG_C 0.01f

#define SCAN_TILE 1024
#define SCAN_NT ((N_NODES + SCAN_TILE - 1) / SCAN_TILE)   // 98
#define NTILES (N_NODES / 16)                             // 6250 exactly
#define HIST_BLOCKS ((N_EDGES + 255) / 256)               // 3907
#define GEMM_BLOCKS 1024
#define DEG_SCALE 16777216.0f                              // 2^24 fixed point

typedef _Float16 half8 __attribute__((ext_vector_type(8)));
typedef float f32x4 __attribute__((ext_vector_type(4)));
typedef int i32x4 __attribute__((ext_vector_type(4)));

__device__ __forceinline__ i32x4 ntload4(const i32x4* p) {
    return __builtin_nontemporal_load(p);
}

// ------- fused: u64 packed histogram (count|deg) + rank  AND  h1 = fp16(x@W1) -------
__global__ void hist_gemm(const int* __restrict__ dst, const float* __restrict__ w,
                          unsigned long long* __restrict__ packed, int* __restrict__ rank,
                          const float* __restrict__ X, const float* __restrict__ W,
                          _Float16* __restrict__ H16) {
    if (blockIdx.x < HIST_BLOCKS) {
        int e = blockIdx.x * 256 + threadIdx.x;
        if (e < N_EDGES) {
            int d = dst[e];
            unsigned long long pk = (1ULL << 40) |
                (unsigned long long)__float2uint_rn(w[e] * DEG_SCALE);
            unsigned long long old = atomicAdd(&packed[d], pk);
            rank[e] = (int)(old >> 40);
        }
        return;
    }
    // ---- GEMM part ----
    const int lane = threadIdx.x & 63;
    const int wave = threadIdx.x >> 6;
    const int q = lane >> 4;
    const int l = lane & 15;
    half8 bfrag[2][4];
#pragma unroll
    for (int kb = 0; kb < 2; ++kb)
#pragma unroll
        for (int t = 0; t < 4; ++t)
#pragma unroll
            for (int j = 0; j < 8; ++j)
                bfrag[kb][t][j] = (_Float16)W[(kb * 32 + q * 8 + j) * 64 + t * 16 + l];

    const int gb = blockIdx.x - HIST_BLOCKS;
    const int waveStride = GEMM_BLOCKS * 4;
    for (int ntile = gb * 4 + wave; ntile < NTILES; ntile += waveStride) {
        const int node0 = ntile * 16;
        const float* arow = X + (size_t)(node0 + l) * 64 + q * 8;
        half8 af0, af1;
#pragma unroll
        for (int j = 0; j < 8; ++j) {
            af0[j] = (_Float16)__builtin_nontemporal_load(&arow[j]);
            af1[j] = (_Float16)__builtin_nontemporal_load(&arow[32 + j]);
        }
        f32x4 acc[4];
#pragma unroll
        for (int t = 0; t < 4; ++t) acc[t] = (f32x4){0.f, 0.f, 0.f, 0.f};
#pragma unroll
        for (int t = 0; t < 4; ++t) {
            acc[t] = __builtin_amdgcn_mfma_f32_16x16x32_f16(af0, bfrag[0][t], acc[t], 0, 0, 0);
            acc[t] = __builtin_amdgcn_mfma_f32_16x16x32_f16(af1, bfrag[1][t], acc[t], 0, 0, 0);
        }
#pragma unroll
        for (int t = 0; t < 4; ++t)
#pragma unroll
            for (int r = 0; r < 4; ++r)
                H16[(size_t)(node0 + q * 4 + r) * 64 + t * 16 + l] = (_Float16)acc[t][r];
    }
}

// ------- scan phase 1, fused with dinv/invdeg computation ----------------
__global__ void scan_p1_dinv(const unsigned long long* __restrict__ packed,
                             int* __restrict__ blocksum, float* __restrict__ dinv,
                             float* __restrict__ invdeg) {
    __shared__ int s[256];
    int base = blockIdx.x * SCAN_TILE;
    int tid = threadIdx.x;
    int sum = 0;
#pragma unroll
    for (int j = 0; j < 4; ++j) {
        int i = base + tid * 4 + j;
        if (i < N_NODES) {
            unsigned long long p = packed[i];
            sum += (int)(p >> 40);
            float d = (float)(p & 0xFFFFFFFFFFULL) * (1.0f / DEG_SCALE) + 1.0f;
            dinv[i] = rsqrtf(d);
            invdeg[i] = 1.0f / d;
        }
    }
    s[tid] = sum;
    __syncthreads();
    for (int off = 128; off; off >>= 1) {
        if (tid < off) s[tid] += s[tid + off];
        __syncthreads();
    }
    if (tid == 0) blocksum[blockIdx.x] = s[0];
}

__global__ void scan_p2(int* __restrict__ blocksum, int* __restrict__ rowptr) {
    __shared__ int s[128];
    int tid = threadIdx.x;
    s[tid] = (tid < SCAN_NT) ? blocksum[tid] : 0;
    __syncthreads();
    if (tid == 0) {
        int run = 0;
        for (int i = 0; i < SCAN_NT; ++i) { int v = s[i]; s[i] = run; run += v; }
        rowptr[N_NODES] = N_EDGES;
    }
    __syncthreads();
    if (tid < SCAN_NT) blocksum[tid] = s[tid];
}

__global__ void scan_p3(const unsigned long long* __restrict__ packed,
                        const int* __restrict__ blocksum, int* __restrict__ rowptr) {
    __shared__ int s[256];
    int base = blockIdx.x * SCAN_TILE;
    int tid = threadIdx.x;
    int v[4];
    int sum = 0;
#pragma unroll
    for (int j = 0; j < 4; ++j) {
        int i = base + tid * 4 + j;
        v[j] = (i < N_NODES) ? (int)(packed[i] >> 40) : 0;
        sum += v[j];
    }
    s[tid] = sum;
    __syncthreads();
    for (int off = 1; off < 256; off <<= 1) {
        int t = (tid >= off) ? s[tid - off] : 0;
        __syncthreads();
        s[tid] += t;
        __syncthreads();
    }
    int run = blocksum[blockIdx.x] + (tid ? s[tid - 1] : 0);
#pragma unroll
    for (int j = 0; j < 4; ++j) {
        int i = base + tid * 4 + j;
        if (i < N_NODES) rowptr[i] = run;
        run += v[j];
    }
}

// ------- atomic-free placement: edata[rowptr[d]+rank[e]] = (src, norm, w, dst) -----
__global__ void sort_scatter(const int* __restrict__ src, const int* __restrict__ dst,
                             const float* __restrict__ w, const float* __restrict__ dinv,
                             const int* __restrict__ rowptr, const int* __restrict__ rank,
                             i32x4* __restrict__ edata) {
    int e = blockIdx.x * blockDim.x + threadIdx.x;
    if (e < N_EDGES) {
        int s = src[e], d = dst[e];
        float we = w[e];
        float norm = dinv[s] * we * dinv[d];
        i32x4 rec;
        rec.x = s; rec.y = __float_as_int(norm);
        rec.z = __float_as_int(we); rec.w = d;
        __builtin_nontemporal_store(rec, &edata[rowptr[d] + rank[e]]);
    }
}

// ------- gather-aggregate 64-dim, unroll-8; nt on the edata stream -----------------
__global__ void agg64_fused(const int* __restrict__ rowptr, const i32x4* __restrict__ edata,
                            const _Float16* __restrict__ H16, const float* __restrict__ invdeg,
                            const float* __restrict__ b1, _Float16* __restrict__ h2h) {
    int node = blockIdx.x * 4 + (threadIdx.x >> 6);
    int lane = threadIdx.x & 63;
    if (node >= N_NODES) return;
    int p = rowptr[node], end = rowptr[node + 1];
    float a0 = 0.f, a1 = 0.f, a2 = 0.f, a3 = 0.f;
    float a4 = 0.f, a5 = 0.f, a6 = 0.f, a7 = 0.f;
    for (; p + 7 < end; p += 8) {
        i32x4 e0 = ntload4(edata + p),     e1 = ntload4(edata + p + 1);
        i32x4 e2 = ntload4(edata + p + 2), e3 = ntload4(edata + p + 3);
        i32x4 e4 = ntload4(edata + p + 4), e5 = ntload4(edata + p + 5);
        i32x4 e6 = ntload4(edata + p + 6), e7 = ntload4(edata + p + 7);
        a0 += __int_as_float(e0.y) * (float)H16[(size_t)e0.x * 64 + lane];
        a1 += __int_as_float(e1.y) * (float)H16[(size_t)e1.x * 64 + lane];
        a2 += __int_as_float(e2.y) * (float)H16[(size_t)e2.x * 64 + lane];
        a3 += __int_as_float(e3.y) * (float)H16[(size_t)e3.x * 64 + lane];
        a4 += __int_as_float(e4.y) * (float)H16[(size_t)e4.x * 64 + lane];
        a5 += __int_as_float(e5.y) * (float)H16[(size_t)e5.x * 64 + lane];
        a6 += __int_as_float(e6.y) * (float)H16[(size_t)e6.x * 64 + lane];
        a7 += __int_as_float(e7.y) * (float)H16[(size_t)e7.x * 64 + lane];
    }
    for (; p + 1 < end; p += 2) {
        i32x4 e0 = ntload4(edata + p), e1 = ntload4(edata + p + 1);
        a0 += __int_as_float(e0.y) * (float)H16[(size_t)e0.x * 64 + lane];
        a1 += __int_as_float(e1.y) * (float)H16[(size_t)e1.x * 64 + lane];
    }
    if (p < end) {
        i32x4 e0 = ntload4(edata + p);
        a0 += __int_as_float(e0.y) * (float)H16[(size_t)e0.x * 64 + lane];
    }
    float v = ((a0 + a1) + (a2 + a3)) + ((a4 + a5) + (a6 + a7)) +
              (float)H16[(size_t)node * 64 + lane] * invdeg[node] + b1[lane];
    __builtin_nontemporal_store((_Float16)fmaxf(v, 0.f), &h2h[(size_t)node * 64 + lane]);
}

// ---------------- hh16 = fp16(h2 @ W2), padded 32-wide rows ----------------
__global__ void linear30(const _Float16* __restrict__ H, const float* __restrict__ W2,
                         __half* __restrict__ HH16) {
    __shared__ float sW[64 * NC];
    __shared__ float sH[8 * 64];
    for (int i = threadIdx.x; i < 64 * NC; i += blockDim.x) sW[i] = W2[i];
    int node0 = blockIdx.x * 8;
    for (int i = threadIdx.x; i < 8 * 64; i += blockDim.x) {
        int n = node0 + (i >> 6);
        sH[i] = (n < N_NODES) ? (float)H[(size_t)n * 64 + (i & 63)] : 0.f;
    }
    __syncthreads();
    int ln = threadIdx.x >> 5;
    int c = threadIdx.x & 31;
    int node = node0 + ln;
    if (node < N_NODES) {
        float acc = 0.f;
        if (c < NC) {
#pragma unroll
            for (int k = 0; k < 64; ++k) acc += sH[ln * 64 + k] * sW[k * NC + c];
        }
        HH16[(size_t)node * NCP + c] = __float2half(acc);
    }
}

// ------- gather-aggregate 30-dim + softmax; software-pipelined edata prefetch ------
__global__ void agg30_softmax_colsum(const int* __restrict__ rowptr, const i32x4* __restrict__ edata,
                                     const __half* __restrict__ HH16,
                                     const float* __restrict__ invdeg,
                                     const float* __restrict__ b2, float* __restrict__ FX,
                                     __half* __restrict__ FX16, float* __restrict__ colsum) {
    const int lane = threadIdx.x & 63;
    const int waveInBlock = threadIdx.x >> 6;
    const int half = lane >> 5;
    const int c = lane & 31;
    const bool activeC = (c < NC);
    const int wavesTotal = gridDim.x * (blockDim.x >> 6);
    const int w0 = blockIdx.x * (blockDim.x >> 6) + waveInBlock;

    const float bb = activeC ? b2[c] : 0.f;
    float lacc = 0.f;

    for (int pair = w0; pair < N_NODES / 2; pair += wavesTotal) {
        const int node = pair * 2 + half;
        int p = rowptr[node], end = rowptr[node + 1];
        float acc0 = 0.f, acc1 = 0.f, acc2 = 0.f, acc3 = 0.f;
        i32x4 c0, c1, c2, c3;
        if (p + 3 < end) {
            c0 = ntload4(edata + p);     c1 = ntload4(edata + p + 1);
            c2 = ntload4(edata + p + 2); c3 = ntload4(edata + p + 3);
        }
        // main loop: prefetch next 4 records while gathering current 4
        for (; p + 7 < end; p += 4) {
            i32x4 n0 = ntload4(edata + p + 4), n1 = ntload4(edata + p + 5);
            i32x4 n2 = ntload4(edata + p + 6), n3 = ntload4(edata + p + 7);
            acc0 += __int_as_float(c0.y) * __half2float(HH16[(size_t)c0.x * NCP + c]);
            acc1 += __int_as_float(c1.y) * __half2float(HH16[(size_t)c1.x * NCP + c]);
            acc2 += __int_as_float(c2.y) * __half2float(HH16[(size_t)c2.x * NCP + c]);
            acc3 += __int_as_float(c3.y) * __half2float(HH16[(size_t)c3.x * NCP + c]);
            c0 = n0; c1 = n1; c2 = n2; c3 = n3;
        }
        if (p + 3 < end) {
            acc0 += __int_as_float(c0.y) * __half2float(HH16[(size_t)c0.x * NCP + c]);
            acc1 += __int_as_float(c1.y) * __half2float(HH16[(size_t)c1.x * NCP + c]);
            acc2 += __int_as_float(c2.y) * __half2float(HH16[(size_t)c2.x * NCP + c]);
            acc3 += __int_as_float(c3.y) * __half2float(HH16[(size_t)c3.x * NCP + c]);
            p += 4;
        }
        for (; p < end; ++p) {
            i32x4 e0 = ntload4(edata + p);
            acc0 += __int_as_float(e0.y) * __half2float(HH16[(size_t)e0.x * NCP + c]);
        }
        float selfv = __half2float(HH16[(size_t)node * NCP + c]);
        float x = activeC ? ((acc0 + acc1) + (acc2 + acc3) + selfv * invdeg[node] + bb)
                          : -INFINITY;
        float mx = x;
        for (int off = 16; off; off >>= 1) mx = fmaxf(mx, __shfl_xor(mx, off));
        float e = activeC ? expf(x - mx) : 0.f;
        float s = e;
        for (int off = 16; off; off >>= 1) s += __shfl_xor(s, off);
        float fx = e / s;
        if (activeC) {
            __builtin_nontemporal_store(fx, &FX[(size_t)node * NC + c]);  // output-only
            FX16[(size_t)node * NCP + c] = __float2half(fx);              // gather table
            lacc += log1pf(-fx * fx);
        } else {
            FX16[(size_t)node * NCP + c] = __float2half(0.f);
        }
    }
    lacc += __shfl_xor(lacc, 32);
    __shared__ float part[4][NC];
    if (half == 0 && activeC) part[waveInBlock][c] = lacc;
    __syncthreads();
    if (threadIdx.x < NC) {
        float v = part[0][threadIdx.x] + part[1][threadIdx.x] +
                  part[2][threadIdx.x] + part[3][threadIdx.x];
        atomicAdd(&colsum[threadIdx.x], v);
    }
}

// ------- edge loss over dst-sorted edges: dst rows hit cache (runs of same dst) ----
// NO device-scope fences here (R7 lesson).
__global__ void edge_loss_sorted(const i32x4* __restrict__ edata, const uint4* __restrict__ FX16u,
                                 float* __restrict__ mse) {
    int e = blockIdx.x * blockDim.x + threadIdx.x;
    float v = 0.f;
    if (e < N_EDGES) {
        i32x4 ed = ntload4(edata + e);
        const uint4* rs = FX16u + (size_t)ed.x * 4;
        const uint4* rd = FX16u + (size_t)ed.w * 4;
        __half2 acc[4];
#pragma unroll
        for (int i = 0; i < 4; ++i) acc[i] = __half2half2(__float2half(0.f));
#pragma unroll
        for (int i = 0; i < 4; ++i) {
            uint4 a = rs[i];
            uint4 b = rd[i];
            acc[0] = __hfma2(*(const __half2*)&a.x, *(const __half2*)&b.x, acc[0]);
            acc[1] = __hfma2(*(const __half2*)&a.y, *(const __half2*)&b.y, acc[1]);
            acc[2] = __hfma2(*(const __half2*)&a.z, *(const __half2*)&b.z, acc[2]);
            acc[3] = __hfma2(*(const __half2*)&a.w, *(const __half2*)&b.w, acc[3]);
        }
        float ff = 0.f;
#pragma unroll
        for (int i = 0; i < 4; ++i)
            ff += __low2float(acc[i]) + __high2float(acc[i]);
        float diff = ff - __int_as_float(ed.z);
        v = diff * diff;
    }
    for (int off = 32; off > 0; off >>= 1) v += __shfl_down(v, off);
    __shared__ float ps[4];
    int lane = threadIdx.x & 63, wv = threadIdx.x >> 6;
    if (lane == 0) ps[wv] = v;
    __syncthreads();
    if (threadIdx.x == 0) atomicAdd(mse, ps[0] + ps[1] + ps[2] + ps[3]);
}

// ---------------- finalize: preg + loss ----------------
__global__ void finalize(const float* __restrict__ colsum, const float* __restrict__ mse,
                         float* __restrict__ out_loss) {
    int c = threadIdx.x;
    float term = 0.f;
    if (c < NC) term = logf(1.0001f - expf(colsum[c]));
    for (int off = 32; off > 0; off >>= 1) term += __shfl_down(term, off);
    if (threadIdx.x == 0) {
        float preg = -term;
        out_loss[0] = mse[0] / (float)N_EDGES + REG_C * preg;
    }
}

extern "C" void kernel_launch(void* const* d_in, const int* in_sizes, int n_in,
                              void* d_out, int out_size, void* d_ws, size_t ws_size,
                              hipStream_t stream) {
    const float* x  = (const float*)d_in[0];
    const int*   ei = (const int*)d_in[1];
    const float* ea = (const float*)d_in[2];
    const float* W1 = (const float*)d_in[3];
    const float* b1 = (const float*)d_in[4];
    const float* W2 = (const float*)d_in[5];
    const float* b2 = (const float*)d_in[6];
    const int* srcI = ei;
    const int* dstI = ei + N_EDGES;

    float* FX   = (float*)d_out;
    float* loss = FX + (size_t)N_NODES * NC;

    // workspace layout -- explicit float-element offsets; edata 16B-aligned
    float* ws = (float*)d_ws;
    float*    dinv   = ws;                            // N
    float*    invdeg = ws + 100000;                   // N
    _Float16* h1h    = (_Float16*)(ws + 200000);      // 64N halves = 3.2M floats
    _Float16* h2h    = (_Float16*)(ws + 3400000);     // 64N halves
    __half*   hh16   = (__half*)(ws + 6600000);       // 32N halves = 1.6M floats
    __half*   fx16   = (__half*)(ws + 8200000);       // 32N halves
    float*    colsum = ws + 9800000;                  // 32
    float*    mse    = ws + 9800032;                  // 1
    int*      rowptr = (int*)(ws + 9800064);          // N+1
    int*      bsum   = (int*)(ws + 9900066);          // 130
    unsigned long long* packed = (unsigned long long*)(ws + 9900200);  // N u64
    int*      rank   = (int*)(ws + 10100200);         // E
    i32x4*    edata  = (i32x4*)(ws + 11100200);       // E i32x4 (offset %4==0)

    hipMemsetAsync(packed, 0, N_NODES * sizeof(unsigned long long), stream);
    hipMemsetAsync(colsum, 0, 34 * sizeof(float), stream);

    hist_gemm<<<HIST_BLOCKS + GEMM_BLOCKS, 256, 0, stream>>>(dstI, ea, packed, rank,
                                                             x, W1, h1h);
    scan_p1_dinv<<<SCAN_NT, 256, 0, stream>>>(packed, bsum, dinv, invdeg);
    scan_p2<<<1, 128, 0, stream>>>(bsum, rowptr);
    scan_p3<<<SCAN_NT, 256, 0, stream>>>(packed, bsum, rowptr);
    sort_scatter<<<(N_EDGES + 255) / 256, 256, 0, stream>>>(srcI, dstI, ea, dinv,
                                                            rowptr, rank, edata);
    agg64_fused<<<(N_NODES + 3) / 4, 256, 0, stream>>>(rowptr, edata, h1h, invdeg, b1, h2h);
    linear30<<<(N_NODES + 7) / 8, 256, 0, stream>>>(h2h, W2, hh16);
    agg30_softmax_colsum<<<4096, 256, 0, stream>>>(rowptr, edata, hh16, invdeg, b2,
                                                   FX, fx16, colsum);
    edge_loss_sorted<<<(N_EDGES + 255) / 256, 256, 0, stream>>>(edata, (const uint4*)fx16, mse);
    finalize<<<1, 64, 0, stream>>>(colsum, mse, loss);
}

// Round 10
// 420.147 us; speedup vs baseline: 1.0176x; 1.0176x over previous
//
#include <hip/hip_runtime.h>
#include <hip/hip_fp16.h>
#include <math.h>

#define N_NODES 100000
#define N_EDGES 1000000
#define IN_DIM 64
#define HID 64
#define NC 30
#define NCP 32              // padded row width for fp16 feature rows (64 B)
#define REG_C 0.01f

#define SCAN_TILE 1024
#define SCAN_NT ((N_NODES + SCAN_TILE - 1) / SCAN_TILE)   // 98
#define NTILES (N_NODES / 16)                             // 6250 exactly
#define DEG_SCALE 16777216.0f                              // 2^24 fixed point

// hist/gemm interleave: groups of 4 blocks = 3 hist + 1 gemm.
// hist blocks needed: 3907 -> 1303 groups -> grid = 5212 blocks (1303 gemm).
#define HG_GROUPS 1303
#define HG_GRID (HG_GROUPS * 4)

typedef _Float16 half8 __attribute__((ext_vector_type(8)));
typedef float f32x4 __attribute__((ext_vector_type(4)));

// ------- fused: u64 packed histogram (count|deg) + rank  AND  h1 = fp16(x@W1) -------
// Roles interleaved (3 hist : 1 gemm per 4-block group) so MFMA work overlaps the
// atomic-latency-bound histogram from dispatch start instead of trailing it.
__global__ void hist_gemm(const int* __restrict__ dst, const float* __restrict__ w,
                          unsigned long long* __restrict__ packed, int* __restrict__ rank,
                          const float* __restrict__ X, const float* __restrict__ W,
                          _Float16* __restrict__ H16) {
    const int g = blockIdx.x;
    const int q = g >> 2, r = g & 3;
    if (r != 3) {
        // ---- histogram part: hist block index = g - q (3 per group) ----
        int hb = g - q;
        int e = hb * 256 + threadIdx.x;
        if (e < N_EDGES) {
            int d = dst[e];
            unsigned long long pk = (1ULL << 40) |
                (unsigned long long)__float2uint_rn(w[e] * DEG_SCALE);
            unsigned long long old = atomicAdd(&packed[d], pk);
            rank[e] = (int)(old >> 40);
        }
        return;
    }
    // ---- GEMM part: gemm block index = q in [0, HG_GROUPS) ----
    const int lane = threadIdx.x & 63;
    const int wave = threadIdx.x >> 6;
    const int qd = lane >> 4;
    const int l = lane & 15;
    half8 bfrag[2][4];
#pragma unroll
    for (int kb = 0; kb < 2; ++kb)
#pragma unroll
        for (int t = 0; t < 4; ++t)
#pragma unroll
            for (int j = 0; j < 8; ++j)
                bfrag[kb][t][j] = (_Float16)W[(kb * 32 + qd * 8 + j) * 64 + t * 16 + l];

    const int waveStride = HG_GROUPS * 4;
    for (int ntile = q * 4 + wave; ntile < NTILES; ntile += waveStride) {
        const int node0 = ntile * 16;
        const float* arow = X + (size_t)(node0 + l) * 64 + qd * 8;
        half8 af0, af1;
#pragma unroll
        for (int j = 0; j < 8; ++j) {
            af0[j] = (_Float16)arow[j];
            af1[j] = (_Float16)arow[32 + j];
        }
        f32x4 acc[4];
#pragma unroll
        for (int t = 0; t < 4; ++t) acc[t] = (f32x4){0.f, 0.f, 0.f, 0.f};
#pragma unroll
        for (int t = 0; t < 4; ++t) {
            acc[t] = __builtin_amdgcn_mfma_f32_16x16x32_f16(af0, bfrag[0][t], acc[t], 0, 0, 0);
            acc[t] = __builtin_amdgcn_mfma_f32_16x16x32_f16(af1, bfrag[1][t], acc[t], 0, 0, 0);
        }
#pragma unroll
        for (int t = 0; t < 4; ++t)
#pragma unroll
            for (int rr = 0; rr < 4; ++rr)
                H16[(size_t)(node0 + qd * 4 + rr) * 64 + t * 16 + l] = (_Float16)acc[t][rr];
    }
}

// ------- scan phase 1, fused with dinv/invdeg computation ----------------
__global__ void scan_p1_dinv(const unsigned long long* __restrict__ packed,
                             int* __restrict__ blocksum, float* __restrict__ dinv,
                             float* __restrict__ invdeg) {
    __shared__ int s[256];
    int base = blockIdx.x * SCAN_TILE;
    int tid = threadIdx.x;
    int sum = 0;
#pragma unroll
    for (int j = 0; j < 4; ++j) {
        int i = base + tid * 4 + j;
        if (i < N_NODES) {
            unsigned long long p = packed[i];
            sum += (int)(p >> 40);
            float d = (float)(p & 0xFFFFFFFFFFULL) * (1.0f / DEG_SCALE) + 1.0f;
            dinv[i] = rsqrtf(d);
            invdeg[i] = 1.0f / d;
        }
    }
    s[tid] = sum;
    __syncthreads();
    for (int off = 128; off; off >>= 1) {
        if (tid < off) s[tid] += s[tid + off];
        __syncthreads();
    }
    if (tid == 0) blocksum[blockIdx.x] = s[0];
}

__global__ void scan_p2(int* __restrict__ blocksum, int* __restrict__ rowptr) {
    __shared__ int s[128];
    int tid = threadIdx.x;
    s[tid] = (tid < SCAN_NT) ? blocksum[tid] : 0;
    __syncthreads();
    if (tid == 0) {
        int run = 0;
        for (int i = 0; i < SCAN_NT; ++i) { int v = s[i]; s[i] = run; run += v; }
        rowptr[N_NODES] = N_EDGES;
    }
    __syncthreads();
    if (tid < SCAN_NT) blocksum[tid] = s[tid];
}

__global__ void scan_p3(const unsigned long long* __restrict__ packed,
                        const int* __restrict__ blocksum, int* __restrict__ rowptr) {
    __shared__ int s[256];
    int base = blockIdx.x * SCAN_TILE;
    int tid = threadIdx.x;
    int v[4];
    int sum = 0;
#pragma unroll
    for (int j = 0; j < 4; ++j) {
        int i = base + tid * 4 + j;
        v[j] = (i < N_NODES) ? (int)(packed[i] >> 40) : 0;
        sum += v[j];
    }
    s[tid] = sum;
    __syncthreads();
    for (int off = 1; off < 256; off <<= 1) {
        int t = (tid >= off) ? s[tid - off] : 0;
        __syncthreads();
        s[tid] += t;
        __syncthreads();
    }
    int run = blocksum[blockIdx.x] + (tid ? s[tid - 1] : 0);
#pragma unroll
    for (int j = 0; j < 4; ++j) {
        int i = base + tid * 4 + j;
        if (i < N_NODES) rowptr[i] = run;
        run += v[j];
    }
}

// ------- atomic-free placement: edata[rowptr[d]+rank[e]] = (src, norm, w, dst) -----
__global__ void sort_scatter(const int* __restrict__ src, const int* __restrict__ dst,
                             const float* __restrict__ w, const float* __restrict__ dinv,
                             const int* __restrict__ rowptr, const int* __restrict__ rank,
                             int4* __restrict__ edata) {
    int e = blockIdx.x * blockDim.x + threadIdx.x;
    if (e < N_EDGES) {
        int s = src[e], d = dst[e];
        float we = w[e];
        float norm = dinv[s] * we * dinv[d];
        edata[rowptr[d] + rank[e]] =
            make_int4(s, __float_as_int(norm), __float_as_int(we), d);
    }
}

// ------- gather-aggregate 64-dim, unroll-8 (8 outstanding misses per wave) ---------
__global__ void agg64_fused(const int* __restrict__ rowptr, const int4* __restrict__ edata,
                            const _Float16* __restrict__ H16, const float* __restrict__ invdeg,
                            const float* __restrict__ b1, _Float16* __restrict__ h2h) {
    int node = blockIdx.x * 4 + (threadIdx.x >> 6);
    int lane = threadIdx.x & 63;
    if (node >= N_NODES) return;
    int p = rowptr[node], end = rowptr[node + 1];
    float a0 = 0.f, a1 = 0.f, a2 = 0.f, a3 = 0.f;
    float a4 = 0.f, a5 = 0.f, a6 = 0.f, a7 = 0.f;
    for (; p + 7 < end; p += 8) {
        int4 e0 = edata[p],     e1 = edata[p + 1], e2 = edata[p + 2], e3 = edata[p + 3];
        int4 e4 = edata[p + 4], e5 = edata[p + 5], e6 = edata[p + 6], e7 = edata[p + 7];
        a0 += __int_as_float(e0.y) * (float)H16[(size_t)e0.x * 64 + lane];
        a1 += __int_as_float(e1.y) * (float)H16[(size_t)e1.x * 64 + lane];
        a2 += __int_as_float(e2.y) * (float)H16[(size_t)e2.x * 64 + lane];
        a3 += __int_as_float(e3.y) * (float)H16[(size_t)e3.x * 64 + lane];
        a4 += __int_as_float(e4.y) * (float)H16[(size_t)e4.x * 64 + lane];
        a5 += __int_as_float(e5.y) * (float)H16[(size_t)e5.x * 64 + lane];
        a6 += __int_as_float(e6.y) * (float)H16[(size_t)e6.x * 64 + lane];
        a7 += __int_as_float(e7.y) * (float)H16[(size_t)e7.x * 64 + lane];
    }
    for (; p + 1 < end; p += 2) {
        int4 e0 = edata[p], e1 = edata[p + 1];
        a0 += __int_as_float(e0.y) * (float)H16[(size_t)e0.x * 64 + lane];
        a1 += __int_as_float(e1.y) * (float)H16[(size_t)e1.x * 64 + lane];
    }
    if (p < end) {
        int4 e0 = edata[p];
        a0 += __int_as_float(e0.y) * (float)H16[(size_t)e0.x * 64 + lane];
    }
    float v = ((a0 + a1) + (a2 + a3)) + ((a4 + a5) + (a6 + a7)) +
              (float)H16[(size_t)node * 64 + lane] * invdeg[node] + b1[lane];
    h2h[(size_t)node * 64 + lane] = (_Float16)fmaxf(v, 0.f);
}

// ---------------- hh16 = fp16(h2 @ W2), padded 32-wide rows ----------------
__global__ void linear30(const _Float16* __restrict__ H, const float* __restrict__ W2,
                         __half* __restrict__ HH16) {
    __shared__ float sW[64 * NC];
    __shared__ float sH[8 * 64];
    for (int i = threadIdx.x; i < 64 * NC; i += blockDim.x) sW[i] = W2[i];
    int node0 = blockIdx.x * 8;
    for (int i = threadIdx.x; i < 8 * 64; i += blockDim.x) {
        int n = node0 + (i >> 6);
        sH[i] = (n < N_NODES) ? (float)H[(size_t)n * 64 + (i & 63)] : 0.f;
    }
    __syncthreads();
    int ln = threadIdx.x >> 5;
    int c = threadIdx.x & 31;
    int node = node0 + ln;
    if (node < N_NODES) {
        float acc = 0.f;
        if (c < NC) {
#pragma unroll
            for (int k = 0; k < 64; ++k) acc += sH[ln * 64 + k] * sW[k * NC + c];
        }
        HH16[(size_t)node * NCP + c] = __float2half(acc);
    }
}

// ------- gather-aggregate 30-dim + softmax, unroll-4; high-TLP grid ---------------
__global__ void agg30_softmax_colsum(const int* __restrict__ rowptr, const int4* __restrict__ edata,
                                     const __half* __restrict__ HH16,
                                     const float* __restrict__ invdeg,
                                     const float* __restrict__ b2, float* __restrict__ FX,
                                     __half* __restrict__ FX16, float* __restrict__ colsum) {
    const int lane = threadIdx.x & 63;
    const int waveInBlock = threadIdx.x >> 6;
    const int half = lane >> 5;
    const int c = lane & 31;
    const bool activeC = (c < NC);
    const int wavesTotal = gridDim.x * (blockDim.x >> 6);
    const int w0 = blockIdx.x * (blockDim.x >> 6) + waveInBlock;

    const float bb = activeC ? b2[c] : 0.f;
    float lacc = 0.f;

    for (int pair = w0; pair < N_NODES / 2; pair += wavesTotal) {
        const int node = pair * 2 + half;
        int p = rowptr[node], end = rowptr[node + 1];
        float acc0 = 0.f, acc1 = 0.f, acc2 = 0.f, acc3 = 0.f;
        for (; p + 3 < end; p += 4) {
            int4 e0 = edata[p],     e1 = edata[p + 1];
            int4 e2 = edata[p + 2], e3 = edata[p + 3];
            acc0 += __int_as_float(e0.y) * __half2float(HH16[(size_t)e0.x * NCP + c]);
            acc1 += __int_as_float(e1.y) * __half2float(HH16[(size_t)e1.x * NCP + c]);
            acc2 += __int_as_float(e2.y) * __half2float(HH16[(size_t)e2.x * NCP + c]);
            acc3 += __int_as_float(e3.y) * __half2float(HH16[(size_t)e3.x * NCP + c]);
        }
        for (; p < end; ++p) {
            int4 e0 = edata[p];
            acc0 += __int_as_float(e0.y) * __half2float(HH16[(size_t)e0.x * NCP + c]);
        }
        float selfv = __half2float(HH16[(size_t)node * NCP + c]);
        float x = activeC ? ((acc0 + acc1) + (acc2 + acc3) + selfv * invdeg[node] + bb)
                          : -INFINITY;
        float mx = x;
        for (int off = 16; off; off >>= 1) mx = fmaxf(mx, __shfl_xor(mx, off));
        float e = activeC ? expf(x - mx) : 0.f;
        float s = e;
        for (int off = 16; off; off >>= 1) s += __shfl_xor(s, off);
        float fx = e / s;
        if (activeC) {
            FX[(size_t)node * NC + c] = fx;
            FX16[(size_t)node * NCP + c] = __float2half(fx);
            lacc += log1pf(-fx * fx);
        } else {
            FX16[(size_t)node * NCP + c] = __float2half(0.f);
        }
    }
    lacc += __shfl_xor(lacc, 32);
    __shared__ float part[4][NC];
    if (half == 0 && activeC) part[waveInBlock][c] = lacc;
    __syncthreads();
    if (threadIdx.x < NC) {
        float v = part[0][threadIdx.x] + part[1][threadIdx.x] +
                  part[2][threadIdx.x] + part[3][threadIdx.x];
        atomicAdd(&colsum[threadIdx.x], v);
    }
}

// ------- edge loss over dst-sorted edges: dst rows hit cache (runs of same dst) ----
// NO device-scope fences here (R7 lesson), no NT (R9 lesson).
__global__ void edge_loss_sorted(const int4* __restrict__ edata, const uint4* __restrict__ FX16u,
                                 float* __restrict__ mse) {
    int e = blockIdx.x * blockDim.x + threadIdx.x;
    float v = 0.f;
    if (e < N_EDGES) {
        int4 ed = edata[e];
        const uint4* rs = FX16u + (size_t)ed.x * 4;
        const uint4* rd = FX16u + (size_t)ed.w * 4;
        __half2 acc[4];
#pragma unroll
        for (int i = 0; i < 4; ++i) acc[i] = __half2half2(__float2half(0.f));
#pragma unroll
        for (int i = 0; i < 4; ++i) {
            uint4 a = rs[i];
            uint4 b = rd[i];
            acc[0] = __hfma2(*(const __half2*)&a.x, *(const __half2*)&b.x, acc[0]);
            acc[1] = __hfma2(*(const __half2*)&a.y, *(const __half2*)&b.y, acc[1]);
            acc[2] = __hfma2(*(const __half2*)&a.z, *(const __half2*)&b.z, acc[2]);
            acc[3] = __hfma2(*(const __half2*)&a.w, *(const __half2*)&b.w, acc[3]);
        }
        float ff = 0.f;
#pragma unroll
        for (int i = 0; i < 4; ++i)
            ff += __low2float(acc[i]) + __high2float(acc[i]);
        float diff = ff - __int_as_float(ed.z);
        v = diff * diff;
    }
    for (int off = 32; off > 0; off >>= 1) v += __shfl_down(v, off);
    __shared__ float ps[4];
    int lane = threadIdx.x & 63, wv = threadIdx.x >> 6;
    if (lane == 0) ps[wv] = v;
    __syncthreads();
    if (threadIdx.x == 0) atomicAdd(mse, ps[0] + ps[1] + ps[2] + ps[3]);
}

// ---------------- finalize: preg + loss ----------------
__global__ void finalize(const float* __restrict__ colsum, const float* __restrict__ mse,
                         float* __restrict__ out_loss) {
    int c = threadIdx.x;
    float term = 0.f;
    if (c < NC) term = logf(1.0001f - expf(colsum[c]));
    for (int off = 32; off > 0; off >>= 1) term += __shfl_down(term, off);
    if (threadIdx.x == 0) {
        float preg = -term;
        out_loss[0] = mse[0] / (float)N_EDGES + REG_C * preg;
    }
}

extern "C" void kernel_launch(void* const* d_in, const int* in_sizes, int n_in,
                              void* d_out, int out_size, void* d_ws, size_t ws_size,
                              hipStream_t stream) {
    const float* x  = (const float*)d_in[0];
    const int*   ei = (const int*)d_in[1];
    const float* ea = (const float*)d_in[2];
    const float* W1 = (const float*)d_in[3];
    const float* b1 = (const float*)d_in[4];
    const float* W2 = (const float*)d_in[5];
    const float* b2 = (const float*)d_in[6];
    const int* srcI = ei;
    const int* dstI = ei + N_EDGES;

    float* FX   = (float*)d_out;
    float* loss = FX + (size_t)N_NODES * NC;

    // workspace layout -- explicit float-element offsets; edata 16B-aligned
    float* ws = (float*)d_ws;
    float*    dinv   = ws;                            // N
    float*    invdeg = ws + 100000;                   // N
    _Float16* h1h    = (_Float16*)(ws + 200000);      // 64N halves = 3.2M floats
    _Float16* h2h    = (_Float16*)(ws + 3400000);     // 64N halves
    __half*   hh16   = (__half*)(ws + 6600000);       // 32N halves = 1.6M floats
    __half*   fx16   = (__half*)(ws + 8200000);       // 32N halves
    float*    colsum = ws + 9800000;                  // 32
    float*    mse    = ws + 9800032;                  // 1
    int*      rowptr = (int*)(ws + 9800064);          // N+1
    int*      bsum   = (int*)(ws + 9900066);          // 130
    unsigned long long* packed = (unsigned long long*)(ws + 9900200);  // N u64
    int*      rank   = (int*)(ws + 10100200);         // E
    int4*     edata  = (int4*)(ws + 11100200);        // E int4 (offset %4==0)

    hipMemsetAsync(packed, 0, N_NODES * sizeof(unsigned long long), stream);
    hipMemsetAsync(colsum, 0, 34 * sizeof(float), stream);

    hist_gemm<<<HG_GRID, 256, 0, stream>>>(dstI, ea, packed, rank, x, W1, h1h);
    scan_p1_dinv<<<SCAN_NT, 256, 0, stream>>>(packed, bsum, dinv, invdeg);
    scan_p2<<<1, 128, 0, stream>>>(bsum, rowptr);
    scan_p3<<<SCAN_NT, 256, 0, stream>>>(packed, bsum, rowptr);
    sort_scatter<<<(N_EDGES + 255) / 256, 256, 0, stream>>>(srcI, dstI, ea, dinv,
                                                            rowptr, rank, edata);
    agg64_fused<<<(N_NODES + 3) / 4, 256, 0, stream>>>(rowptr, edata, h1h, invdeg, b1, h2h);
    linear30<<<(N_NODES + 7) / 8, 256, 0, stream>>>(h2h, W2, hh16);
    agg30_softmax_colsum<<<8192, 256, 0, stream>>>(rowptr, edata, hh16, invdeg, b2,
                                                   FX, fx16, colsum);
    edge_loss_sorted<<<(N_EDGES + 255) / 256, 256, 0, stream>>>(edata, (const uint4*)fx16, mse);
    finalize<<<1, 64, 0, stream>>>(colsum, mse, loss);
}

// Round 11
// 323.348 us; speedup vs baseline: 1.3223x; 1.2994x over previous
//
#include <hip/hip_runtime.h>
#include <hip/hip_fp16.h>
#include <math.h>

#define N_NODES 100000
#define N_EDGES 1000000
#define IN_DIM 64
#define HID 64
#define NC 30
#define NCP 32              // padded row width for fp16 feature rows (64 B)
#define REG_C 0.01f

#define SCAN_TILE 1024
#define SCAN_NT ((N_NODES + SCAN_TILE - 1) / SCAN_TILE)   // 98
#define NTILES (N_NODES / 16)                             // 6250 exactly
#define DEG_SCALE 16777216.0f                              // 2^24 fixed point

// hist/gemm interleave: groups of 4 blocks = 3 hist + 1 gemm.
#define HG_GROUPS 1303
#define HG_GRID (HG_GROUPS * 4)

typedef _Float16 half8 __attribute__((ext_vector_type(8)));
typedef float f32x4 __attribute__((ext_vector_type(4)));

// ------- fused: u64 packed histogram (count|deg) + rank  AND  h1 = fp16(x@W1) -------
__global__ void hist_gemm(const int* __restrict__ dst, const float* __restrict__ w,
                          unsigned long long* __restrict__ packed, int* __restrict__ rank,
                          const float* __restrict__ X, const float* __restrict__ W,
                          _Float16* __restrict__ H16) {
    const int g = blockIdx.x;
    const int q = g >> 2, r = g & 3;
    if (r != 3) {
        int hb = g - q;                    // 3 hist blocks per group
        int e = hb * 256 + threadIdx.x;
        if (e < N_EDGES) {
            int d = dst[e];
            unsigned long long pk = (1ULL << 40) |
                (unsigned long long)__float2uint_rn(w[e] * DEG_SCALE);
            unsigned long long old = atomicAdd(&packed[d], pk);
            rank[e] = (int)(old >> 40);
        }
        return;
    }
    // ---- GEMM part ----
    const int lane = threadIdx.x & 63;
    const int wave = threadIdx.x >> 6;
    const int qd = lane >> 4;
    const int l = lane & 15;
    half8 bfrag[2][4];
#pragma unroll
    for (int kb = 0; kb < 2; ++kb)
#pragma unroll
        for (int t = 0; t < 4; ++t)
#pragma unroll
            for (int j = 0; j < 8; ++j)
                bfrag[kb][t][j] = (_Float16)W[(kb * 32 + qd * 8 + j) * 64 + t * 16 + l];

    const int waveStride = HG_GROUPS * 4;
    for (int ntile = q * 4 + wave; ntile < NTILES; ntile += waveStride) {
        const int node0 = ntile * 16;
        const float* arow = X + (size_t)(node0 + l) * 64 + qd * 8;
        half8 af0, af1;
#pragma unroll
        for (int j = 0; j < 8; ++j) {
            af0[j] = (_Float16)arow[j];
            af1[j] = (_Float16)arow[32 + j];
        }
        f32x4 acc[4];
#pragma unroll
        for (int t = 0; t < 4; ++t) acc[t] = (f32x4){0.f, 0.f, 0.f, 0.f};
#pragma unroll
        for (int t = 0; t < 4; ++t) {
            acc[t] = __builtin_amdgcn_mfma_f32_16x16x32_f16(af0, bfrag[0][t], acc[t], 0, 0, 0);
            acc[t] = __builtin_amdgcn_mfma_f32_16x16x32_f16(af1, bfrag[1][t], acc[t], 0, 0, 0);
        }
#pragma unroll
        for (int t = 0; t < 4; ++t)
#pragma unroll
            for (int rr = 0; rr < 4; ++rr)
                H16[(size_t)(node0 + qd * 4 + rr) * 64 + t * 16 + l] = (_Float16)acc[t][rr];
    }
}

// ------- scan phase 1, fused with dinv/invdeg computation ----------------
__global__ void scan_p1_dinv(const unsigned long long* __restrict__ packed,
                             int* __restrict__ blocksum, float* __restrict__ dinv,
                             float* __restrict__ invdeg) {
    __shared__ int s[256];
    int base = blockIdx.x * SCAN_TILE;
    int tid = threadIdx.x;
    int sum = 0;
#pragma unroll
    for (int j = 0; j < 4; ++j) {
        int i = base + tid * 4 + j;
        if (i < N_NODES) {
            unsigned long long p = packed[i];
            sum += (int)(p >> 40);
            float d = (float)(p & 0xFFFFFFFFFFULL) * (1.0f / DEG_SCALE) + 1.0f;
            dinv[i] = rsqrtf(d);
            invdeg[i] = 1.0f / d;
        }
    }
    s[tid] = sum;
    __syncthreads();
    for (int off = 128; off; off >>= 1) {
        if (tid < off) s[tid] += s[tid + off];
        __syncthreads();
    }
    if (tid == 0) blocksum[blockIdx.x] = s[0];
}

__global__ void scan_p2(int* __restrict__ blocksum, int* __restrict__ rowptr) {
    __shared__ int s[128];
    int tid = threadIdx.x;
    s[tid] = (tid < SCAN_NT) ? blocksum[tid] : 0;
    __syncthreads();
    if (tid == 0) {
        int run = 0;
        for (int i = 0; i < SCAN_NT; ++i) { int v = s[i]; s[i] = run; run += v; }
        rowptr[N_NODES] = N_EDGES;
    }
    __syncthreads();
    if (tid < SCAN_NT) blocksum[tid] = s[tid];
}

__global__ void scan_p3(const unsigned long long* __restrict__ packed,
                        const int* __restrict__ blocksum, int* __restrict__ rowptr) {
    __shared__ int s[256];
    int base = blockIdx.x * SCAN_TILE;
    int tid = threadIdx.x;
    int v[4];
    int sum = 0;
#pragma unroll
    for (int j = 0; j < 4; ++j) {
        int i = base + tid * 4 + j;
        v[j] = (i < N_NODES) ? (int)(packed[i] >> 40) : 0;
        sum += v[j];
    }
    s[tid] = sum;
    __syncthreads();
    for (int off = 1; off < 256; off <<= 1) {
        int t = (tid >= off) ? s[tid - off] : 0;
        __syncthreads();
        s[tid] += t;
        __syncthreads();
    }
    int run = blocksum[blockIdx.x] + (tid ? s[tid - 1] : 0);
#pragma unroll
    for (int j = 0; j < 4; ++j) {
        int i = base + tid * 4 + j;
        if (i < N_NODES) rowptr[i] = run;
        run += v[j];
    }
}

// ------- atomic-free placement: slim records --------------------------------------
// edata2[pos] = {src, norm}  (8 B, read by both agg passes)
// wd[pos]     = {w, dst}     (8 B, read only by edge_loss)
__global__ void sort_scatter(const int* __restrict__ src, const int* __restrict__ dst,
                             const float* __restrict__ w, const float* __restrict__ dinv,
                             const int* __restrict__ rowptr, const int* __restrict__ rank,
                             int2* __restrict__ edata2, int2* __restrict__ wd) {
    int e = blockIdx.x * blockDim.x + threadIdx.x;
    if (e < N_EDGES) {
        int s = src[e], d = dst[e];
        float we = w[e];
        float norm = dinv[s] * we * dinv[d];
        int pos = rowptr[d] + rank[e];
        edata2[pos] = make_int2(s, __float_as_int(norm));
        wd[pos] = make_int2(__float_as_int(we), d);
    }
}

// ------- gather-aggregate 64-dim, unroll-8 ----------------------------------------
__global__ void agg64_fused(const int* __restrict__ rowptr, const int2* __restrict__ edata2,
                            const _Float16* __restrict__ H16, const float* __restrict__ invdeg,
                            const float* __restrict__ b1, _Float16* __restrict__ h2h) {
    int node = blockIdx.x * 4 + (threadIdx.x >> 6);
    int lane = threadIdx.x & 63;
    if (node >= N_NODES) return;
    int p = rowptr[node], end = rowptr[node + 1];
    float a0 = 0.f, a1 = 0.f, a2 = 0.f, a3 = 0.f;
    float a4 = 0.f, a5 = 0.f, a6 = 0.f, a7 = 0.f;
    for (; p + 7 < end; p += 8) {
        int2 e0 = edata2[p],     e1 = edata2[p + 1], e2 = edata2[p + 2], e3 = edata2[p + 3];
        int2 e4 = edata2[p + 4], e5 = edata2[p + 5], e6 = edata2[p + 6], e7 = edata2[p + 7];
        a0 += __int_as_float(e0.y) * (float)H16[(size_t)e0.x * 64 + lane];
        a1 += __int_as_float(e1.y) * (float)H16[(size_t)e1.x * 64 + lane];
        a2 += __int_as_float(e2.y) * (float)H16[(size_t)e2.x * 64 + lane];
        a3 += __int_as_float(e3.y) * (float)H16[(size_t)e3.x * 64 + lane];
        a4 += __int_as_float(e4.y) * (float)H16[(size_t)e4.x * 64 + lane];
        a5 += __int_as_float(e5.y) * (float)H16[(size_t)e5.x * 64 + lane];
        a6 += __int_as_float(e6.y) * (float)H16[(size_t)e6.x * 64 + lane];
        a7 += __int_as_float(e7.y) * (float)H16[(size_t)e7.x * 64 + lane];
    }
    for (; p + 1 < end; p += 2) {
        int2 e0 = edata2[p], e1 = edata2[p + 1];
        a0 += __int_as_float(e0.y) * (float)H16[(size_t)e0.x * 64 + lane];
        a1 += __int_as_float(e1.y) * (float)H16[(size_t)e1.x * 64 + lane];
    }
    if (p < end) {
        int2 e0 = edata2[p];
        a0 += __int_as_float(e0.y) * (float)H16[(size_t)e0.x * 64 + lane];
    }
    float v = ((a0 + a1) + (a2 + a3)) + ((a4 + a5) + (a6 + a7)) +
              (float)H16[(size_t)node * 64 + lane] * invdeg[node] + b1[lane];
    h2h[(size_t)node * 64 + lane] = (_Float16)fmaxf(v, 0.f);
}

// ---------------- hh16 = fp16(h2 @ W2), padded 32-wide rows ----------------
__global__ void linear30(const _Float16* __restrict__ H, const float* __restrict__ W2,
                         __half* __restrict__ HH16) {
    __shared__ float sW[64 * NC];
    __shared__ float sH[8 * 64];
    for (int i = threadIdx.x; i < 64 * NC; i += blockDim.x) sW[i] = W2[i];
    int node0 = blockIdx.x * 8;
    for (int i = threadIdx.x; i < 8 * 64; i += blockDim.x) {
        int n = node0 + (i >> 6);
        sH[i] = (n < N_NODES) ? (float)H[(size_t)n * 64 + (i & 63)] : 0.f;
    }
    __syncthreads();
    int ln = threadIdx.x >> 5;
    int c = threadIdx.x & 31;
    int node = node0 + ln;
    if (node < N_NODES) {
        float acc = 0.f;
        if (c < NC) {
#pragma unroll
            for (int k = 0; k < 64; ++k) acc += sH[ln * 64 + k] * sW[k * NC + c];
        }
        HH16[(size_t)node * NCP + c] = __float2half(acc);
    }
}

// ------- gather-aggregate 30-dim + softmax, unroll-4; grid 4096 (empirical best) ---
// colsum spread over 64 slots: chain depth 4096/64=64 instead of 4096.
__global__ void agg30_softmax_colsum(const int* __restrict__ rowptr, const int2* __restrict__ edata2,
                                     const __half* __restrict__ HH16,
                                     const float* __restrict__ invdeg,
                                     const float* __restrict__ b2, float* __restrict__ FX,
                                     __half* __restrict__ FX16, float* __restrict__ colsum_part) {
    const int lane = threadIdx.x & 63;
    const int waveInBlock = threadIdx.x >> 6;
    const int half = lane >> 5;
    const int c = lane & 31;
    const bool activeC = (c < NC);
    const int wavesTotal = gridDim.x * (blockDim.x >> 6);
    const int w0 = blockIdx.x * (blockDim.x >> 6) + waveInBlock;

    const float bb = activeC ? b2[c] : 0.f;
    float lacc = 0.f;

    for (int pair = w0; pair < N_NODES / 2; pair += wavesTotal) {
        const int node = pair * 2 + half;
        int p = rowptr[node], end = rowptr[node + 1];
        float acc0 = 0.f, acc1 = 0.f, acc2 = 0.f, acc3 = 0.f;
        for (; p + 3 < end; p += 4) {
            int2 e0 = edata2[p],     e1 = edata2[p + 1];
            int2 e2 = edata2[p + 2], e3 = edata2[p + 3];
            acc0 += __int_as_float(e0.y) * __half2float(HH16[(size_t)e0.x * NCP + c]);
            acc1 += __int_as_float(e1.y) * __half2float(HH16[(size_t)e1.x * NCP + c]);
            acc2 += __int_as_float(e2.y) * __half2float(HH16[(size_t)e2.x * NCP + c]);
            acc3 += __int_as_float(e3.y) * __half2float(HH16[(size_t)e3.x * NCP + c]);
        }
        for (; p < end; ++p) {
            int2 e0 = edata2[p];
            acc0 += __int_as_float(e0.y) * __half2float(HH16[(size_t)e0.x * NCP + c]);
        }
        float selfv = __half2float(HH16[(size_t)node * NCP + c]);
        float x = activeC ? ((acc0 + acc1) + (acc2 + acc3) + selfv * invdeg[node] + bb)
                          : -INFINITY;
        float mx = x;
        for (int off = 16; off; off >>= 1) mx = fmaxf(mx, __shfl_xor(mx, off));
        float e = activeC ? expf(x - mx) : 0.f;
        float s = e;
        for (int off = 16; off; off >>= 1) s += __shfl_xor(s, off);
        float fx = e / s;
        if (activeC) {
            FX[(size_t)node * NC + c] = fx;
            FX16[(size_t)node * NCP + c] = __float2half(fx);
            lacc += log1pf(-fx * fx);
        } else {
            FX16[(size_t)node * NCP + c] = __float2half(0.f);
        }
    }
    lacc += __shfl_xor(lacc, 32);
    __shared__ float part[4][NC];
    if (half == 0 && activeC) part[waveInBlock][c] = lacc;
    __syncthreads();
    if (threadIdx.x < NC) {
        float v = part[0][threadIdx.x] + part[1][threadIdx.x] +
                  part[2][threadIdx.x] + part[3][threadIdx.x];
        atomicAdd(&colsum_part[(blockIdx.x & 63) * 32 + threadIdx.x], v);
    }
}

// ------- edge loss over dst-sorted edges (slim 8B+8B records) ----------------------
// mse spread over 64 slots. No fences (R7), no NT (R9).
__global__ void edge_loss_sorted(const int2* __restrict__ edata2, const int2* __restrict__ wd,
                                 const uint4* __restrict__ FX16u, float* __restrict__ mse_part) {
    int e = blockIdx.x * blockDim.x + threadIdx.x;
    float v = 0.f;
    if (e < N_EDGES) {
        int2 sn = edata2[e];
        int2 wdv = wd[e];
        const uint4* rs = FX16u + (size_t)sn.x * 4;
        const uint4* rd = FX16u + (size_t)wdv.y * 4;
        __half2 acc[4];
#pragma unroll
        for (int i = 0; i < 4; ++i) acc[i] = __half2half2(__float2half(0.f));
#pragma unroll
        for (int i = 0; i < 4; ++i) {
            uint4 a = rs[i];
            uint4 b = rd[i];
            acc[0] = __hfma2(*(const __half2*)&a.x, *(const __half2*)&b.x, acc[0]);
            acc[1] = __hfma2(*(const __half2*)&a.y, *(const __half2*)&b.y, acc[1]);
            acc[2] = __hfma2(*(const __half2*)&a.z, *(const __half2*)&b.z, acc[2]);
            acc[3] = __hfma2(*(const __half2*)&a.w, *(const __half2*)&b.w, acc[3]);
        }
        float ff = 0.f;
#pragma unroll
        for (int i = 0; i < 4; ++i)
            ff += __low2float(acc[i]) + __high2float(acc[i]);
        float diff = ff - __int_as_float(wdv.x);
        v = diff * diff;
    }
    for (int off = 32; off > 0; off >>= 1) v += __shfl_down(v, off);
    __shared__ float ps[4];
    int lane = threadIdx.x & 63, wv = threadIdx.x >> 6;
    if (lane == 0) ps[wv] = v;
    __syncthreads();
    if (threadIdx.x == 0)
        atomicAdd(&mse_part[blockIdx.x & 63], ps[0] + ps[1] + ps[2] + ps[3]);
}

// ---------------- finalize: sum 64-slot partials, preg + loss ----------------
__global__ void finalize(const float* __restrict__ colsum_part, const float* __restrict__ mse_part,
                         float* __restrict__ out_loss) {
    int t = threadIdx.x;          // 64 threads
    float m = mse_part[t];
    for (int off = 32; off > 0; off >>= 1) m += __shfl_down(m, off);
    float term = 0.f;
    if (t < NC) {
        float s = 0.f;
        for (int k = 0; k < 64; ++k) s += colsum_part[k * 32 + t];
        term = logf(1.0001f - expf(s));
    }
    for (int off = 32; off > 0; off >>= 1) term += __shfl_down(term, off);
    if (t == 0)
        out_loss[0] = m / (float)N_EDGES - REG_C * term;
}

extern "C" void kernel_launch(void* const* d_in, const int* in_sizes, int n_in,
                              void* d_out, int out_size, void* d_ws, size_t ws_size,
                              hipStream_t stream) {
    const float* x  = (const float*)d_in[0];
    const int*   ei = (const int*)d_in[1];
    const float* ea = (const float*)d_in[2];
    const float* W1 = (const float*)d_in[3];
    const float* b1 = (const float*)d_in[4];
    const float* W2 = (const float*)d_in[5];
    const float* b2 = (const float*)d_in[6];
    const int* srcI = ei;
    const int* dstI = ei + N_EDGES;

    float* FX   = (float*)d_out;
    float* loss = FX + (size_t)N_NODES * NC;

    // workspace layout -- explicit float-element offsets; int2/u64 offsets even
    float* ws = (float*)d_ws;
    float*    dinv   = ws;                            // N
    float*    invdeg = ws + 100000;                   // N
    _Float16* h1h    = (_Float16*)(ws + 200000);      // 64N halves = 3.2M floats
    _Float16* h2h    = (_Float16*)(ws + 3400000);     // 64N halves
    __half*   hh16   = (__half*)(ws + 6600000);       // 32N halves = 1.6M floats
    __half*   fx16   = (__half*)(ws + 8200000);       // 32N halves
    float*    colsum_part = ws + 9800000;             // 64*32 = 2048
    float*    mse_part    = ws + 9802048;             // 64
    int*      rowptr = (int*)(ws + 9802112);          // N+1
    int*      bsum   = (int*)(ws + 9902114);          // 130 (+pad to even)
    unsigned long long* packed = (unsigned long long*)(ws + 9902244);  // N u64 (even)
    int*      rank   = (int*)(ws + 10102244);         // E
    int2*     edata2 = (int2*)(ws + 11102244);        // E int2 (even offset)
    int2*     wd     = (int2*)(ws + 13102244);        // E int2 (even offset)

    hipMemsetAsync(packed, 0, N_NODES * sizeof(unsigned long long), stream);
    hipMemsetAsync(colsum_part, 0, (2048 + 64) * sizeof(float), stream);

    hist_gemm<<<HG_GRID, 256, 0, stream>>>(dstI, ea, packed, rank, x, W1, h1h);
    scan_p1_dinv<<<SCAN_NT, 256, 0, stream>>>(packed, bsum, dinv, invdeg);
    scan_p2<<<1, 128, 0, stream>>>(bsum, rowptr);
    scan_p3<<<SCAN_NT, 256, 0, stream>>>(packed, bsum, rowptr);
    sort_scatter<<<(N_EDGES + 255) / 256, 256, 0, stream>>>(srcI, dstI, ea, dinv,
                                                            rowptr, rank, edata2, wd);
    agg64_fused<<<(N_NODES + 3) / 4, 256, 0, stream>>>(rowptr, edata2, h1h, invdeg, b1, h2h);
    linear30<<<(N_NODES + 7) / 8, 256, 0, stream>>>(h2h, W2, hh16);
    agg30_softmax_colsum<<<4096, 256, 0, stream>>>(rowptr, edata2, hh16, invdeg, b2,
                                                   FX, fx16, colsum_part);
    edge_loss_sorted<<<(N_EDGES + 255) / 256, 256, 0, stream>>>(edata2, wd,
                                                                (const uint4*)fx16, mse_part);
    finalize<<<1, 64, 0, stream>>>(colsum_part, mse_part, loss);
}

// Round 12
// 318.218 us; speedup vs baseline: 1.3436x; 1.0161x over previous
//
#include <hip/hip_runtime.h>
#include <hip/hip_fp16.h>
#include <math.h>

#define N_NODES 100000
#define N_EDGES 1000000
#define IN_DIM 64
#define HID 64
#define NC 30
#define NCP 32              // padded row width for fp16/fp8 feature rows
#define REG_C 0.01f

#define SCAN_TILE 1024
#define SCAN_NT ((N_NODES + SCAN_TILE - 1) / SCAN_TILE)   // 98
#define NTILES (N_NODES / 16)                             // 6250 exactly
#define DEG_SCALE 16777216.0f                              // 2^24 fixed point

// hist/gemm interleave: groups of 4 blocks = 3 hist + 1 gemm.
#define HG_GROUPS 1303
#define HG_GRID (HG_GROUPS * 4)

typedef _Float16 half8 __attribute__((ext_vector_type(8)));
typedef float f32x4 __attribute__((ext_vector_type(4)));

__device__ __forceinline__ unsigned char enc_fp8(float v) {
    return (unsigned char)(__builtin_amdgcn_cvt_pk_fp8_f32(v, v, 0, false) & 0xFF);
}
__device__ __forceinline__ float dec_fp8(unsigned char b) {
    return __builtin_amdgcn_cvt_f32_fp8((int)b, 0);
}
__device__ __forceinline__ float dot4_fp8(unsigned a, unsigned b) {
    float s = __builtin_amdgcn_cvt_f32_fp8((int)a, 0) * __builtin_amdgcn_cvt_f32_fp8((int)b, 0);
    s += __builtin_amdgcn_cvt_f32_fp8((int)a, 1) * __builtin_amdgcn_cvt_f32_fp8((int)b, 1);
    s += __builtin_amdgcn_cvt_f32_fp8((int)a, 2) * __builtin_amdgcn_cvt_f32_fp8((int)b, 2);
    s += __builtin_amdgcn_cvt_f32_fp8((int)a, 3) * __builtin_amdgcn_cvt_f32_fp8((int)b, 3);
    return s;
}

// ------- fused: u64 packed histogram (count|deg) + rank  AND  h1 = fp8(x@W1) -------
__global__ void hist_gemm(const int* __restrict__ dst, const float* __restrict__ w,
                          unsigned long long* __restrict__ packed, int* __restrict__ rank,
                          const float* __restrict__ X, const float* __restrict__ W,
                          unsigned char* __restrict__ H8) {
    const int g = blockIdx.x;
    const int q = g >> 2, r = g & 3;
    if (r != 3) {
        int hb = g - q;                    // 3 hist blocks per group
        int e = hb * 256 + threadIdx.x;
        if (e < N_EDGES) {
            int d = dst[e];
            unsigned long long pk = (1ULL << 40) |
                (unsigned long long)__float2uint_rn(w[e] * DEG_SCALE);
            unsigned long long old = atomicAdd(&packed[d], pk);
            rank[e] = (int)(old >> 40);
        }
        return;
    }
    // ---- GEMM part ----
    const int lane = threadIdx.x & 63;
    const int wave = threadIdx.x >> 6;
    const int qd = lane >> 4;
    const int l = lane & 15;
    half8 bfrag[2][4];
#pragma unroll
    for (int kb = 0; kb < 2; ++kb)
#pragma unroll
        for (int t = 0; t < 4; ++t)
#pragma unroll
            for (int j = 0; j < 8; ++j)
                bfrag[kb][t][j] = (_Float16)W[(kb * 32 + qd * 8 + j) * 64 + t * 16 + l];

    const int waveStride = HG_GROUPS * 4;
    for (int ntile = q * 4 + wave; ntile < NTILES; ntile += waveStride) {
        const int node0 = ntile * 16;
        const float* arow = X + (size_t)(node0 + l) * 64 + qd * 8;
        half8 af0, af1;
#pragma unroll
        for (int j = 0; j < 8; ++j) {
            af0[j] = (_Float16)arow[j];
            af1[j] = (_Float16)arow[32 + j];
        }
        f32x4 acc[4];
#pragma unroll
        for (int t = 0; t < 4; ++t) acc[t] = (f32x4){0.f, 0.f, 0.f, 0.f};
#pragma unroll
        for (int t = 0; t < 4; ++t) {
            acc[t] = __builtin_amdgcn_mfma_f32_16x16x32_f16(af0, bfrag[0][t], acc[t], 0, 0, 0);
            acc[t] = __builtin_amdgcn_mfma_f32_16x16x32_f16(af1, bfrag[1][t], acc[t], 0, 0, 0);
        }
#pragma unroll
        for (int t = 0; t < 4; ++t)
#pragma unroll
            for (int rr = 0; rr < 4; ++rr)
                H8[(size_t)(node0 + qd * 4 + rr) * 64 + t * 16 + l] = enc_fp8(acc[t][rr]);
    }
}

// ------- scan phase 1, fused with dinv/invdeg computation ----------------
__global__ void scan_p1_dinv(const unsigned long long* __restrict__ packed,
                             int* __restrict__ blocksum, float* __restrict__ dinv,
                             float* __restrict__ invdeg) {
    __shared__ int s[256];
    int base = blockIdx.x * SCAN_TILE;
    int tid = threadIdx.x;
    int sum = 0;
#pragma unroll
    for (int j = 0; j < 4; ++j) {
        int i = base + tid * 4 + j;
        if (i < N_NODES) {
            unsigned long long p = packed[i];
            sum += (int)(p >> 40);
            float d = (float)(p & 0xFFFFFFFFFFULL) * (1.0f / DEG_SCALE) + 1.0f;
            dinv[i] = rsqrtf(d);
            invdeg[i] = 1.0f / d;
        }
    }
    s[tid] = sum;
    __syncthreads();
    for (int off = 128; off; off >>= 1) {
        if (tid < off) s[tid] += s[tid + off];
        __syncthreads();
    }
    if (tid == 0) blocksum[blockIdx.x] = s[0];
}

__global__ void scan_p2(int* __restrict__ blocksum, int* __restrict__ rowptr) {
    __shared__ int s[128];
    int tid = threadIdx.x;
    s[tid] = (tid < SCAN_NT) ? blocksum[tid] : 0;
    __syncthreads();
    if (tid == 0) {
        int run = 0;
        for (int i = 0; i < SCAN_NT; ++i) { int v = s[i]; s[i] = run; run += v; }
        rowptr[N_NODES] = N_EDGES;
    }
    __syncthreads();
    if (tid < SCAN_NT) blocksum[tid] = s[tid];
}

__global__ void scan_p3(const unsigned long long* __restrict__ packed,
                        const int* __restrict__ blocksum, int* __restrict__ rowptr) {
    __shared__ int s[256];
    int base = blockIdx.x * SCAN_TILE;
    int tid = threadIdx.x;
    int v[4];
    int sum = 0;
#pragma unroll
    for (int j = 0; j < 4; ++j) {
        int i = base + tid * 4 + j;
        v[j] = (i < N_NODES) ? (int)(packed[i] >> 40) : 0;
        sum += v[j];
    }
    s[tid] = sum;
    __syncthreads();
    for (int off = 1; off < 256; off <<= 1) {
        int t = (tid >= off) ? s[tid - off] : 0;
        __syncthreads();
        s[tid] += t;
        __syncthreads();
    }
    int run = blocksum[blockIdx.x] + (tid ? s[tid - 1] : 0);
#pragma unroll
    for (int j = 0; j < 4; ++j) {
        int i = base + tid * 4 + j;
        if (i < N_NODES) rowptr[i] = run;
        run += v[j];
    }
}

// ------- atomic-free placement: slim records --------------------------------------
__global__ void sort_scatter(const int* __restrict__ src, const int* __restrict__ dst,
                             const float* __restrict__ w, const float* __restrict__ dinv,
                             const int* __restrict__ rowptr, const int* __restrict__ rank,
                             int2* __restrict__ edata2, int2* __restrict__ wd) {
    int e = blockIdx.x * blockDim.x + threadIdx.x;
    if (e < N_EDGES) {
        int s = src[e], d = dst[e];
        float we = w[e];
        float norm = dinv[s] * we * dinv[d];
        int pos = rowptr[d] + rank[e];
        edata2[pos] = make_int2(s, __float_as_int(norm));
        wd[pos] = make_int2(__float_as_int(we), d);
    }
}

// ------- gather-aggregate 64-dim from fp8 rows (64 B = 1 line/edge), unroll-8 ------
__global__ void agg64_fused(const int* __restrict__ rowptr, const int2* __restrict__ edata2,
                            const unsigned char* __restrict__ H8, const float* __restrict__ invdeg,
                            const float* __restrict__ b1, _Float16* __restrict__ h2h) {
    int node = blockIdx.x * 4 + (threadIdx.x >> 6);
    int lane = threadIdx.x & 63;
    if (node >= N_NODES) return;
    int p = rowptr[node], end = rowptr[node + 1];
    float a0 = 0.f, a1 = 0.f, a2 = 0.f, a3 = 0.f;
    float a4 = 0.f, a5 = 0.f, a6 = 0.f, a7 = 0.f;
    for (; p + 7 < end; p += 8) {
        int2 e0 = edata2[p],     e1 = edata2[p + 1], e2 = edata2[p + 2], e3 = edata2[p + 3];
        int2 e4 = edata2[p + 4], e5 = edata2[p + 5], e6 = edata2[p + 6], e7 = edata2[p + 7];
        a0 += __int_as_float(e0.y) * dec_fp8(H8[(size_t)e0.x * 64 + lane]);
        a1 += __int_as_float(e1.y) * dec_fp8(H8[(size_t)e1.x * 64 + lane]);
        a2 += __int_as_float(e2.y) * dec_fp8(H8[(size_t)e2.x * 64 + lane]);
        a3 += __int_as_float(e3.y) * dec_fp8(H8[(size_t)e3.x * 64 + lane]);
        a4 += __int_as_float(e4.y) * dec_fp8(H8[(size_t)e4.x * 64 + lane]);
        a5 += __int_as_float(e5.y) * dec_fp8(H8[(size_t)e5.x * 64 + lane]);
        a6 += __int_as_float(e6.y) * dec_fp8(H8[(size_t)e6.x * 64 + lane]);
        a7 += __int_as_float(e7.y) * dec_fp8(H8[(size_t)e7.x * 64 + lane]);
    }
    for (; p + 1 < end; p += 2) {
        int2 e0 = edata2[p], e1 = edata2[p + 1];
        a0 += __int_as_float(e0.y) * dec_fp8(H8[(size_t)e0.x * 64 + lane]);
        a1 += __int_as_float(e1.y) * dec_fp8(H8[(size_t)e1.x * 64 + lane]);
    }
    if (p < end) {
        int2 e0 = edata2[p];
        a0 += __int_as_float(e0.y) * dec_fp8(H8[(size_t)e0.x * 64 + lane]);
    }
    float v = ((a0 + a1) + (a2 + a3)) + ((a4 + a5) + (a6 + a7)) +
              dec_fp8(H8[(size_t)node * 64 + lane]) * invdeg[node] + b1[lane];
    h2h[(size_t)node * 64 + lane] = (_Float16)fmaxf(v, 0.f);
}

// ---------------- hh16 = fp16(h2 @ W2), padded 32-wide rows (accuracy-critical) ----
__global__ void linear30(const _Float16* __restrict__ H, const float* __restrict__ W2,
                         __half* __restrict__ HH16) {
    __shared__ float sW[64 * NC];
    __shared__ float sH[8 * 64];
    for (int i = threadIdx.x; i < 64 * NC; i += blockDim.x) sW[i] = W2[i];
    int node0 = blockIdx.x * 8;
    for (int i = threadIdx.x; i < 8 * 64; i += blockDim.x) {
        int n = node0 + (i >> 6);
        sH[i] = (n < N_NODES) ? (float)H[(size_t)n * 64 + (i & 63)] : 0.f;
    }
    __syncthreads();
    int ln = threadIdx.x >> 5;
    int c = threadIdx.x & 31;
    int node = node0 + ln;
    if (node < N_NODES) {
        float acc = 0.f;
        if (c < NC) {
#pragma unroll
            for (int k = 0; k < 64; ++k) acc += sH[ln * 64 + k] * sW[k * NC + c];
        }
        HH16[(size_t)node * NCP + c] = __float2half(acc);
    }
}

// ------- gather-aggregate 30-dim + softmax, unroll-4; writes FX fp32 + fx8 table ---
__global__ void agg30_softmax_colsum(const int* __restrict__ rowptr, const int2* __restrict__ edata2,
                                     const __half* __restrict__ HH16,
                                     const float* __restrict__ invdeg,
                                     const float* __restrict__ b2, float* __restrict__ FX,
                                     unsigned char* __restrict__ FX8,
                                     float* __restrict__ colsum_part) {
    const int lane = threadIdx.x & 63;
    const int waveInBlock = threadIdx.x >> 6;
    const int half = lane >> 5;
    const int c = lane & 31;
    const bool activeC = (c < NC);
    const int wavesTotal = gridDim.x * (blockDim.x >> 6);
    const int w0 = blockIdx.x * (blockDim.x >> 6) + waveInBlock;

    const float bb = activeC ? b2[c] : 0.f;
    float lacc = 0.f;

    for (int pair = w0; pair < N_NODES / 2; pair += wavesTotal) {
        const int node = pair * 2 + half;
        int p = rowptr[node], end = rowptr[node + 1];
        float acc0 = 0.f, acc1 = 0.f, acc2 = 0.f, acc3 = 0.f;
        for (; p + 3 < end; p += 4) {
            int2 e0 = edata2[p],     e1 = edata2[p + 1];
            int2 e2 = edata2[p + 2], e3 = edata2[p + 3];
            acc0 += __int_as_float(e0.y) * __half2float(HH16[(size_t)e0.x * NCP + c]);
            acc1 += __int_as_float(e1.y) * __half2float(HH16[(size_t)e1.x * NCP + c]);
            acc2 += __int_as_float(e2.y) * __half2float(HH16[(size_t)e2.x * NCP + c]);
            acc3 += __int_as_float(e3.y) * __half2float(HH16[(size_t)e3.x * NCP + c]);
        }
        for (; p < end; ++p) {
            int2 e0 = edata2[p];
            acc0 += __int_as_float(e0.y) * __half2float(HH16[(size_t)e0.x * NCP + c]);
        }
        float selfv = __half2float(HH16[(size_t)node * NCP + c]);
        float x = activeC ? ((acc0 + acc1) + (acc2 + acc3) + selfv * invdeg[node] + bb)
                          : -INFINITY;
        float mx = x;
        for (int off = 16; off; off >>= 1) mx = fmaxf(mx, __shfl_xor(mx, off));
        float e = activeC ? expf(x - mx) : 0.f;
        float s = e;
        for (int off = 16; off; off >>= 1) s += __shfl_xor(s, off);
        float fx = e / s;
        if (activeC) {
            FX[(size_t)node * NC + c] = fx;
            FX8[(size_t)node * NCP + c] = enc_fp8(fx);
            lacc += log1pf(-fx * fx);
        } else {
            FX8[(size_t)node * NCP + c] = 0;   // fp8 +0 pad
        }
    }
    lacc += __shfl_xor(lacc, 32);
    __shared__ float part[4][NC];
    if (half == 0 && activeC) part[waveInBlock][c] = lacc;
    __syncthreads();
    if (threadIdx.x < NC) {
        float v = part[0][threadIdx.x] + part[1][threadIdx.x] +
                  part[2][threadIdx.x] + part[3][threadIdx.x];
        atomicAdd(&colsum_part[(blockIdx.x & 63) * 32 + threadIdx.x], v);
    }
}

// ------- edge loss over dst-sorted edges; fp8 FX table (3.2 MB, L2-resident) -------
// No fences (R7), no NT (R9). mse spread over 64 slots (R11).
__global__ void edge_loss_sorted(const int2* __restrict__ edata2, const int2* __restrict__ wd,
                                 const unsigned char* __restrict__ FX8,
                                 float* __restrict__ mse_part) {
    int e = blockIdx.x * blockDim.x + threadIdx.x;
    float v = 0.f;
    if (e < N_EDGES) {
        int2 sn = edata2[e];
        int2 wdv = wd[e];
        const uint4* rs = (const uint4*)(FX8 + (size_t)sn.x * NCP);
        const uint4* rd = (const uint4*)(FX8 + (size_t)wdv.y * NCP);
        uint4 a0 = rs[0], a1 = rs[1];
        uint4 b0 = rd[0], b1 = rd[1];
        float ff = dot4_fp8(a0.x, b0.x) + dot4_fp8(a0.y, b0.y) +
                   dot4_fp8(a0.z, b0.z) + dot4_fp8(a0.w, b0.w) +
                   dot4_fp8(a1.x, b1.x) + dot4_fp8(a1.y, b1.y) +
                   dot4_fp8(a1.z, b1.z) + dot4_fp8(a1.w, b1.w);
        float diff = ff - __int_as_float(wdv.x);
        v = diff * diff;
    }
    for (int off = 32; off > 0; off >>= 1) v += __shfl_down(v, off);
    __shared__ float ps[4];
    int lane = threadIdx.x & 63, wv = threadIdx.x >> 6;
    if (lane == 0) ps[wv] = v;
    __syncthreads();
    if (threadIdx.x == 0)
        atomicAdd(&mse_part[blockIdx.x & 63], ps[0] + ps[1] + ps[2] + ps[3]);
}

// ---------------- finalize: sum 64-slot partials, preg + loss ----------------
__global__ void finalize(const float* __restrict__ colsum_part, const float* __restrict__ mse_part,
                         float* __restrict__ out_loss) {
    int t = threadIdx.x;          // 64 threads
    float m = mse_part[t];
    for (int off = 32; off > 0; off >>= 1) m += __shfl_down(m, off);
    float term = 0.f;
    if (t < NC) {
        float s = 0.f;
        for (int k = 0; k < 64; ++k) s += colsum_part[k * 32 + t];
        term = logf(1.0001f - expf(s));
    }
    for (int off = 32; off > 0; off >>= 1) term += __shfl_down(term, off);
    if (t == 0)
        out_loss[0] = m / (float)N_EDGES - REG_C * term;
}

extern "C" void kernel_launch(void* const* d_in, const int* in_sizes, int n_in,
                              void* d_out, int out_size, void* d_ws, size_t ws_size,
                              hipStream_t stream) {
    const float* x  = (const float*)d_in[0];
    const int*   ei = (const int*)d_in[1];
    const float* ea = (const float*)d_in[2];
    const float* W1 = (const float*)d_in[3];
    const float* b1 = (const float*)d_in[4];
    const float* W2 = (const float*)d_in[5];
    const float* b2 = (const float*)d_in[6];
    const int* srcI = ei;
    const int* dstI = ei + N_EDGES;

    float* FX   = (float*)d_out;
    float* loss = FX + (size_t)N_NODES * NC;

    // workspace layout -- explicit float-element offsets; int2/u64 offsets even
    float* ws = (float*)d_ws;
    float*         dinv   = ws;                        // N
    float*         invdeg = ws + 100000;               // N
    unsigned char* h8     = (unsigned char*)(ws + 200000);   // 64N bytes = 1.6M floats
    _Float16*      h2h    = (_Float16*)(ws + 1800000); // 64N halves = 3.2M floats
    __half*        hh16   = (__half*)(ws + 5000000);   // 32N halves = 1.6M floats
    unsigned char* fx8    = (unsigned char*)(ws + 6600000);  // 32N bytes = 0.8M floats
    float*         colsum_part = ws + 7400000;         // 64*32 = 2048
    float*         mse_part    = ws + 7402048;         // 64
    int*           rowptr = (int*)(ws + 7402112);      // N+1
    int*           bsum   = (int*)(ws + 7502114);      // 130
    unsigned long long* packed = (unsigned long long*)(ws + 7502244);  // N u64 (even)
    int*           rank   = (int*)(ws + 7702244);      // E
    int2*          edata2 = (int2*)(ws + 8702244);     // E int2 (even offset)
    int2*          wd     = (int2*)(ws + 10702244);    // E int2 (even offset)

    hipMemsetAsync(packed, 0, N_NODES * sizeof(unsigned long long), stream);
    hipMemsetAsync(colsum_part, 0, (2048 + 64) * sizeof(float), stream);

    hist_gemm<<<HG_GRID, 256, 0, stream>>>(dstI, ea, packed, rank, x, W1, h8);
    scan_p1_dinv<<<SCAN_NT, 256, 0, stream>>>(packed, bsum, dinv, invdeg);
    scan_p2<<<1, 128, 0, stream>>>(bsum, rowptr);
    scan_p3<<<SCAN_NT, 256, 0, stream>>>(packed, bsum, rowptr);
    sort_scatter<<<(N_EDGES + 255) / 256, 256, 0, stream>>>(srcI, dstI, ea, dinv,
                                                            rowptr, rank, edata2, wd);
    agg64_fused<<<(N_NODES + 3) / 4, 256, 0, stream>>>(rowptr, edata2, h8, invdeg, b1, h2h);
    linear30<<<(N_NODES + 7) / 8, 256, 0, stream>>>(h2h, W2, hh16);
    agg30_softmax_colsum<<<4096, 256, 0, stream>>>(rowptr, edata2, hh16, invdeg, b2,
                                                   FX, fx8, colsum_part);
    edge_loss_sorted<<<(N_EDGES + 255) / 256, 256, 0, stream>>>(edata2, wd, fx8, mse_part);
    finalize<<<1, 64, 0, stream>>>(colsum_part, mse_part, loss);
}

// Round 13
// 302.961 us; speedup vs baseline: 1.4112x; 1.0504x over previous
//
#include <hip/hip_runtime.h>
#include <hip/hip_fp16.h>
#include <math.h>

#define N_NODES 100000
#define N_EDGES 1000000
#define IN_DIM 64
#define HID 64
#define NC 30
#define NCP 32              // padded row width for fp16/fp8 feature rows
#define REG_C 0.01f

#define NTILES (N_NODES / 16)     // 6250
#define NBUCK 391                 // coarse bucket = dst >> 8 (256 nodes/bucket)
#define EPB_A 2048                // edges per hist block
#define NBLK_A 489                // ceil(1M / 2048)
#define GEMM_BLOCKS 512

typedef _Float16 half8 __attribute__((ext_vector_type(8)));
typedef float f32x4 __attribute__((ext_vector_type(4)));

__device__ __forceinline__ unsigned char enc_fp8(float v) {
    return (unsigned char)(__builtin_amdgcn_cvt_pk_fp8_f32(v, v, 0, false) & 0xFF);
}
__device__ __forceinline__ float dec_fp8(unsigned char b) {
    return __builtin_amdgcn_cvt_f32_fp8((int)b, 0);
}
__device__ __forceinline__ float dot4_fp8(unsigned a, unsigned b) {
    float s = __builtin_amdgcn_cvt_f32_fp8((int)a, 0) * __builtin_amdgcn_cvt_f32_fp8((int)b, 0);
    s += __builtin_amdgcn_cvt_f32_fp8((int)a, 1) * __builtin_amdgcn_cvt_f32_fp8((int)b, 1);
    s += __builtin_amdgcn_cvt_f32_fp8((int)a, 2) * __builtin_amdgcn_cvt_f32_fp8((int)b, 2);
    s += __builtin_amdgcn_cvt_f32_fp8((int)a, 3) * __builtin_amdgcn_cvt_f32_fp8((int)b, 3);
    return s;
}

// ------- fused: per-block LDS bucket histogram (NO global atomics) + h1=fp8(x@W1) --
__global__ void hist_gemm(const int* __restrict__ dst, int* __restrict__ histT,
                          const float* __restrict__ X, const float* __restrict__ W,
                          unsigned char* __restrict__ H8) {
    if (blockIdx.x < NBLK_A) {
        __shared__ int cnt[NBUCK];
        for (int i = threadIdx.x; i < NBUCK; i += 256) cnt[i] = 0;
        __syncthreads();
        int e0 = blockIdx.x * EPB_A;
#pragma unroll
        for (int j = 0; j < 8; ++j) {
            int e = e0 + j * 256 + threadIdx.x;
            if (e < N_EDGES) atomicAdd(&cnt[dst[e] >> 8], 1);
        }
        __syncthreads();
        for (int b = threadIdx.x; b < NBUCK; b += 256)
            histT[b * NBLK_A + blockIdx.x] = cnt[b];
        return;
    }
    // ---- GEMM part ----
    const int lane = threadIdx.x & 63;
    const int wave = threadIdx.x >> 6;
    const int qd = lane >> 4;
    const int l = lane & 15;
    half8 bfrag[2][4];
#pragma unroll
    for (int kb = 0; kb < 2; ++kb)
#pragma unroll
        for (int t = 0; t < 4; ++t)
#pragma unroll
            for (int j = 0; j < 8; ++j)
                bfrag[kb][t][j] = (_Float16)W[(kb * 32 + qd * 8 + j) * 64 + t * 16 + l];

    const int gb = blockIdx.x - NBLK_A;
    const int waveStride = GEMM_BLOCKS * 4;
    for (int ntile = gb * 4 + wave; ntile < NTILES; ntile += waveStride) {
        const int node0 = ntile * 16;
        const float* arow = X + (size_t)(node0 + l) * 64 + qd * 8;
        half8 af0, af1;
#pragma unroll
        for (int j = 0; j < 8; ++j) {
            af0[j] = (_Float16)arow[j];
            af1[j] = (_Float16)arow[32 + j];
        }
        f32x4 acc[4];
#pragma unroll
        for (int t = 0; t < 4; ++t) acc[t] = (f32x4){0.f, 0.f, 0.f, 0.f};
#pragma unroll
        for (int t = 0; t < 4; ++t) {
            acc[t] = __builtin_amdgcn_mfma_f32_16x16x32_f16(af0, bfrag[0][t], acc[t], 0, 0, 0);
            acc[t] = __builtin_amdgcn_mfma_f32_16x16x32_f16(af1, bfrag[1][t], acc[t], 0, 0, 0);
        }
#pragma unroll
        for (int t = 0; t < 4; ++t)
#pragma unroll
            for (int rr = 0; rr < 4; ++rr)
                H8[(size_t)(node0 + qd * 4 + rr) * 64 + t * 16 + l] = enc_fp8(acc[t][rr]);
    }
}

// ------- scanA: per bucket, exclusive scan of per-block counts (LDS-staged) --------
__global__ void scanA(int* __restrict__ histT, int* __restrict__ bucketTotal) {
    __shared__ int s[NBLK_A];
    int b = blockIdx.x;
    for (int i = threadIdx.x; i < NBLK_A; i += 256) s[i] = histT[b * NBLK_A + i];
    __syncthreads();
    if (threadIdx.x == 0) {
        int run = 0;
        for (int i = 0; i < NBLK_A; ++i) { int t = s[i]; s[i] = run; run += t; }
        bucketTotal[b] = run;
    }
    __syncthreads();
    for (int i = threadIdx.x; i < NBLK_A; i += 256) histT[b * NBLK_A + i] = s[i];
}

// ------- scanB: exclusive scan of bucket totals -> bucketBase ----------------------
__global__ void scanB(const int* __restrict__ bucketTotal, int* __restrict__ bucketBase) {
    __shared__ int s[NBUCK];
    for (int i = threadIdx.x; i < NBUCK; i += 256) s[i] = bucketTotal[i];
    __syncthreads();
    if (threadIdx.x == 0) {
        int run = 0;
        for (int i = 0; i < NBUCK; ++i) { int t = s[i]; s[i] = run; run += t; }
    }
    __syncthreads();
    for (int i = threadIdx.x; i < NBUCK; i += 256) bucketBase[i] = s[i];
    if (threadIdx.x == 0) bucketBase[NBUCK] = N_EDGES;
}

// ------- scatter into coarse bucket regions (LDS cursors, no global atomics) -------
__global__ void scatter_coarse(const int* __restrict__ src, const int* __restrict__ dst,
                               const float* __restrict__ w, const int* __restrict__ histT,
                               const int* __restrict__ bucketBase,
                               int2* __restrict__ sw, unsigned char* __restrict__ dl) {
    __shared__ int cur[NBUCK];
    int bl = blockIdx.x;
    for (int b = threadIdx.x; b < NBUCK; b += 256)
        cur[b] = bucketBase[b] + histT[b * NBLK_A + bl];
    __syncthreads();
    int e0 = bl * EPB_A;
#pragma unroll
    for (int j = 0; j < 8; ++j) {
        int e = e0 + j * 256 + threadIdx.x;
        if (e < N_EDGES) {
            int d = dst[e];
            int pos = atomicAdd(&cur[d >> 8], 1);
            sw[pos] = make_int2(src[e], __float_as_int(w[e]));
            dl[pos] = (unsigned char)(d & 255);
        }
    }
}

// ------- bs1: per-bucket degree accumulation (LDS) + dinv/invdeg/rowptr ------------
__global__ void bucket_deg(const int2* __restrict__ sw, const unsigned char* __restrict__ dl,
                           const int* __restrict__ bucketBase, float* __restrict__ dinv,
                           float* __restrict__ invdeg, int* __restrict__ rowptr) {
    __shared__ int cnt[256];
    __shared__ float degf[256];
    __shared__ int sc[256];
    int b = blockIdx.x, tid = threadIdx.x;
    cnt[tid] = 0; degf[tid] = 0.f;
    __syncthreads();
    int p0 = bucketBase[b], p1 = bucketBase[b + 1];
    for (int p = p0 + tid; p < p1; p += 256) {
        int d = dl[p];
        atomicAdd(&cnt[d], 1);
        atomicAdd(&degf[d], __int_as_float(sw[p].y));
    }
    __syncthreads();
    sc[tid] = cnt[tid];
    __syncthreads();
    for (int off = 1; off < 256; off <<= 1) {
        int t = (tid >= off) ? sc[tid - off] : 0;
        __syncthreads();
        sc[tid] += t;
        __syncthreads();
    }
    int node = b * 256 + tid;
    if (node < N_NODES) {
        float d = degf[tid] + 1.0f;       // self-loop
        dinv[node] = rsqrtf(d);
        invdeg[node] = 1.0f / d;
        rowptr[node] = p0 + sc[tid] - cnt[tid];   // exclusive
    }
    if (b == 0 && tid == 0) rowptr[N_NODES] = N_EDGES;
}

// ------- bs2: final within-bucket scatter; norm computed (dinv complete) -----------
// Emits edata2/wd byte-identical in layout to R12 -> downstream kernels unchanged.
__global__ void bucket_scatter(const int2* __restrict__ sw, const unsigned char* __restrict__ dl,
                               const int* __restrict__ bucketBase, const int* __restrict__ rowptr,
                               const float* __restrict__ dinv,
                               int2* __restrict__ edata2, int2* __restrict__ wd) {
    __shared__ int cur[256];
    __shared__ float ldinv[256];
    int b = blockIdx.x, tid = threadIdx.x;
    int node = b * 256 + tid;
    if (node < N_NODES) { cur[tid] = rowptr[node]; ldinv[tid] = dinv[node]; }
    __syncthreads();
    int p0 = bucketBase[b], p1 = bucketBase[b + 1];
    for (int p = p0 + tid; p < p1; p += 256) {
        int d = dl[p];
        int2 r = sw[p];
        float wv = __int_as_float(r.y);
        float norm = dinv[r.x] * wv * ldinv[d];
        int pos = atomicAdd(&cur[d], 1);
        edata2[pos] = make_int2(r.x, __float_as_int(norm));
        wd[pos] = make_int2(r.y, b * 256 + d);
    }
}

// ------- gather-aggregate 64-dim from fp8 rows (64 B = 1 line/edge), unroll-8 ------
__global__ void agg64_fused(const int* __restrict__ rowptr, const int2* __restrict__ edata2,
                            const unsigned char* __restrict__ H8, const float* __restrict__ invdeg,
                            const float* __restrict__ b1, _Float16* __restrict__ h2h) {
    int node = blockIdx.x * 4 + (threadIdx.x >> 6);
    int lane = threadIdx.x & 63;
    if (node >= N_NODES) return;
    int p = rowptr[node], end = rowptr[node + 1];
    float a0 = 0.f, a1 = 0.f, a2 = 0.f, a3 = 0.f;
    float a4 = 0.f, a5 = 0.f, a6 = 0.f, a7 = 0.f;
    for (; p + 7 < end; p += 8) {
        int2 e0 = edata2[p],     e1 = edata2[p + 1], e2 = edata2[p + 2], e3 = edata2[p + 3];
        int2 e4 = edata2[p + 4], e5 = edata2[p + 5], e6 = edata2[p + 6], e7 = edata2[p + 7];
        a0 += __int_as_float(e0.y) * dec_fp8(H8[(size_t)e0.x * 64 + lane]);
        a1 += __int_as_float(e1.y) * dec_fp8(H8[(size_t)e1.x * 64 + lane]);
        a2 += __int_as_float(e2.y) * dec_fp8(H8[(size_t)e2.x * 64 + lane]);
        a3 += __int_as_float(e3.y) * dec_fp8(H8[(size_t)e3.x * 64 + lane]);
        a4 += __int_as_float(e4.y) * dec_fp8(H8[(size_t)e4.x * 64 + lane]);
        a5 += __int_as_float(e5.y) * dec_fp8(H8[(size_t)e5.x * 64 + lane]);
        a6 += __int_as_float(e6.y) * dec_fp8(H8[(size_t)e6.x * 64 + lane]);
        a7 += __int_as_float(e7.y) * dec_fp8(H8[(size_t)e7.x * 64 + lane]);
    }
    for (; p + 1 < end; p += 2) {
        int2 e0 = edata2[p], e1 = edata2[p + 1];
        a0 += __int_as_float(e0.y) * dec_fp8(H8[(size_t)e0.x * 64 + lane]);
        a1 += __int_as_float(e1.y) * dec_fp8(H8[(size_t)e1.x * 64 + lane]);
    }
    if (p < end) {
        int2 e0 = edata2[p];
        a0 += __int_as_float(e0.y) * dec_fp8(H8[(size_t)e0.x * 64 + lane]);
    }
    float v = ((a0 + a1) + (a2 + a3)) + ((a4 + a5) + (a6 + a7)) +
              dec_fp8(H8[(size_t)node * 64 + lane]) * invdeg[node] + b1[lane];
    h2h[(size_t)node * 64 + lane] = (_Float16)fmaxf(v, 0.f);
}

// ---------------- hh16 = fp16(h2 @ W2), padded 32-wide rows (accuracy-critical) ----
__global__ void linear30(const _Float16* __restrict__ H, const float* __restrict__ W2,
                         __half* __restrict__ HH16) {
    __shared__ float sW[64 * NC];
    __shared__ float sH[8 * 64];
    for (int i = threadIdx.x; i < 64 * NC; i += blockDim.x) sW[i] = W2[i];
    int node0 = blockIdx.x * 8;
    for (int i = threadIdx.x; i < 8 * 64; i += blockDim.x) {
        int n = node0 + (i >> 6);
        sH[i] = (n < N_NODES) ? (float)H[(size_t)n * 64 + (i & 63)] : 0.f;
    }
    __syncthreads();
    int ln = threadIdx.x >> 5;
    int c = threadIdx.x & 31;
    int node = node0 + ln;
    if (node < N_NODES) {
        float acc = 0.f;
        if (c < NC) {
#pragma unroll
            for (int k = 0; k < 64; ++k) acc += sH[ln * 64 + k] * sW[k * NC + c];
        }
        HH16[(size_t)node * NCP + c] = __float2half(acc);
    }
}

// ------- gather-aggregate 30-dim + softmax, unroll-4; writes FX fp32 + fx8 table ---
__global__ void agg30_softmax_colsum(const int* __restrict__ rowptr, const int2* __restrict__ edata2,
                                     const __half* __restrict__ HH16,
                                     const float* __restrict__ invdeg,
                                     const float* __restrict__ b2, float* __restrict__ FX,
                                     unsigned char* __restrict__ FX8,
                                     float* __restrict__ colsum_part) {
    const int lane = threadIdx.x & 63;
    const int waveInBlock = threadIdx.x >> 6;
    const int half = lane >> 5;
    const int c = lane & 31;
    const bool activeC = (c < NC);
    const int wavesTotal = gridDim.x * (blockDim.x >> 6);
    const int w0 = blockIdx.x * (blockDim.x >> 6) + waveInBlock;

    const float bb = activeC ? b2[c] : 0.f;
    float lacc = 0.f;

    for (int pair = w0; pair < N_NODES / 2; pair += wavesTotal) {
        const int node = pair * 2 + half;
        int p = rowptr[node], end = rowptr[node + 1];
        float acc0 = 0.f, acc1 = 0.f, acc2 = 0.f, acc3 = 0.f;
        for (; p + 3 < end; p += 4) {
            int2 e0 = edata2[p],     e1 = edata2[p + 1];
            int2 e2 = edata2[p + 2], e3 = edata2[p + 3];
            acc0 += __int_as_float(e0.y) * __half2float(HH16[(size_t)e0.x * NCP + c]);
            acc1 += __int_as_float(e1.y) * __half2float(HH16[(size_t)e1.x * NCP + c]);
            acc2 += __int_as_float(e2.y) * __half2float(HH16[(size_t)e2.x * NCP + c]);
            acc3 += __int_as_float(e3.y) * __half2float(HH16[(size_t)e3.x * NCP + c]);
        }
        for (; p < end; ++p) {
            int2 e0 = edata2[p];
            acc0 += __int_as_float(e0.y) * __half2float(HH16[(size_t)e0.x * NCP + c]);
        }
        float selfv = __half2float(HH16[(size_t)node * NCP + c]);
        float x = activeC ? ((acc0 + acc1) + (acc2 + acc3) + selfv * invdeg[node] + bb)
                          : -INFINITY;
        float mx = x;
        for (int off = 16; off; off >>= 1) mx = fmaxf(mx, __shfl_xor(mx, off));
        float e = activeC ? expf(x - mx) : 0.f;
        float s = e;
        for (int off = 16; off; off >>= 1) s += __shfl_xor(s, off);
        float fx = e / s;
        if (activeC) {
            FX[(size_t)node * NC + c] = fx;
            FX8[(size_t)node * NCP + c] = enc_fp8(fx);
            lacc += log1pf(-fx * fx);
        } else {
            FX8[(size_t)node * NCP + c] = 0;   // fp8 +0 pad
        }
    }
    lacc += __shfl_xor(lacc, 32);
    __shared__ float part[4][NC];
    if (half == 0 && activeC) part[waveInBlock][c] = lacc;
    __syncthreads();
    if (threadIdx.x < NC) {
        float v = part[0][threadIdx.x] + part[1][threadIdx.x] +
                  part[2][threadIdx.x] + part[3][threadIdx.x];
        atomicAdd(&colsum_part[(blockIdx.x & 63) * 32 + threadIdx.x], v);
    }
}

// ------- edge loss over dst-sorted edges; fp8 FX table (3.2 MB, L2-resident) -------
// No fences (R7), no NT (R9). mse spread over 64 slots (R11).
__global__ void edge_loss_sorted(const int2* __restrict__ edata2, const int2* __restrict__ wd,
                                 const unsigned char* __restrict__ FX8,
                                 float* __restrict__ mse_part) {
    int e = blockIdx.x * blockDim.x + threadIdx.x;
    float v = 0.f;
    if (e < N_EDGES) {
        int2 sn = edata2[e];
        int2 wdv = wd[e];
        const uint4* rs = (const uint4*)(FX8 + (size_t)sn.x * NCP);
        const uint4* rd = (const uint4*)(FX8 + (size_t)wdv.y * NCP);
        uint4 a0 = rs[0], a1 = rs[1];
        uint4 b0 = rd[0], b1 = rd[1];
        float ff = dot4_fp8(a0.x, b0.x) + dot4_fp8(a0.y, b0.y) +
                   dot4_fp8(a0.z, b0.z) + dot4_fp8(a0.w, b0.w) +
                   dot4_fp8(a1.x, b1.x) + dot4_fp8(a1.y, b1.y) +
                   dot4_fp8(a1.z, b1.z) + dot4_fp8(a1.w, b1.w);
        float diff = ff - __int_as_float(wdv.x);
        v = diff * diff;
    }
    for (int off = 32; off > 0; off >>= 1) v += __shfl_down(v, off);
    __shared__ float ps[4];
    int lane = threadIdx.x & 63, wv = threadIdx.x >> 6;
    if (lane == 0) ps[wv] = v;
    __syncthreads();
    if (threadIdx.x == 0)
        atomicAdd(&mse_part[blockIdx.x & 63], ps[0] + ps[1] + ps[2] + ps[3]);
}

// ---------------- finalize: sum 64-slot partials, preg + loss ----------------
__global__ void finalize(const float* __restrict__ colsum_part, const float* __restrict__ mse_part,
                         float* __restrict__ out_loss) {
    int t = threadIdx.x;          // 64 threads
    float m = mse_part[t];
    for (int off = 32; off > 0; off >>= 1) m += __shfl_down(m, off);
    float term = 0.f;
    if (t < NC) {
        float s = 0.f;
        for (int k = 0; k < 64; ++k) s += colsum_part[k * 32 + t];
        term = logf(1.0001f - expf(s));
    }
    for (int off = 32; off > 0; off >>= 1) term += __shfl_down(term, off);
    if (t == 0)
        out_loss[0] = m / (float)N_EDGES - REG_C * term;
}

extern "C" void kernel_launch(void* const* d_in, const int* in_sizes, int n_in,
                              void* d_out, int out_size, void* d_ws, size_t ws_size,
                              hipStream_t stream) {
    const float* x  = (const float*)d_in[0];
    const int*   ei = (const int*)d_in[1];
    const float* ea = (const float*)d_in[2];
    const float* W1 = (const float*)d_in[3];
    const float* b1 = (const float*)d_in[4];
    const float* W2 = (const float*)d_in[5];
    const float* b2 = (const float*)d_in[6];
    const int* srcI = ei;
    const int* dstI = ei + N_EDGES;

    float* FX   = (float*)d_out;
    float* loss = FX + (size_t)N_NODES * NC;

    // workspace layout -- explicit float-element offsets; int2 offsets even
    float* ws = (float*)d_ws;
    float*         dinv   = ws;                              // N
    float*         invdeg = ws + 100000;                     // N
    unsigned char* h8     = (unsigned char*)(ws + 200000);   // 64N bytes
    _Float16*      h2h    = (_Float16*)(ws + 1800000);       // 64N halves
    __half*        hh16   = (__half*)(ws + 5000000);         // 32N halves
    unsigned char* fx8    = (unsigned char*)(ws + 6600000);  // 32N bytes
    float*         colsum_part = ws + 7400000;               // 2048
    float*         mse_part    = ws + 7402048;               // 64
    int*           rowptr = (int*)(ws + 7402112);            // N+1
    int*           histT  = (int*)(ws + 7502114);            // NBUCK*NBLK_A = 191199
    int*           bucketTotal = (int*)(ws + 7693314);       // 391
    int*           bucketBase  = (int*)(ws + 7693706);       // 392
    int2*          sw     = (int2*)(ws + 7694098);           // E int2 (even ✓)
    unsigned char* dl     = (unsigned char*)(ws + 9694098);  // E bytes
    int2*          edata2 = (int2*)(ws + 9944098);           // E int2 (even ✓)
    int2*          wd     = (int2*)(ws + 11944098);          // E int2 (even ✓)

    hipMemsetAsync(colsum_part, 0, (2048 + 64) * sizeof(float), stream);

    hist_gemm<<<NBLK_A + GEMM_BLOCKS, 256, 0, stream>>>(dstI, histT, x, W1, h8);
    scanA<<<NBUCK, 256, 0, stream>>>(histT, bucketTotal);
    scanB<<<1, 256, 0, stream>>>(bucketTotal, bucketBase);
    scatter_coarse<<<NBLK_A, 256, 0, stream>>>(srcI, dstI, ea, histT, bucketBase, sw, dl);
    bucket_deg<<<NBUCK, 256, 0, stream>>>(sw, dl, bucketBase, dinv, invdeg, rowptr);
    bucket_scatter<<<NBUCK, 256, 0, stream>>>(sw, dl, bucketBase, rowptr, dinv, edata2, wd);
    agg64_fused<<<(N_NODES + 3) / 4, 256, 0, stream>>>(rowptr, edata2, h8, invdeg, b1, h2h);
    linear30<<<(N_NODES + 7) / 8, 256, 0, stream>>>(h2h, W2, hh16);
    agg30_softmax_colsum<<<4096, 256, 0, stream>>>(rowptr, edata2, hh16, invdeg, b2,
                                                   FX, fx8, colsum_part);
    edge_loss_sorted<<<(N_EDGES + 255) / 256, 256, 0, stream>>>(edata2, wd, fx8, mse_part);
    finalize<<<1, 64, 0, stream>>>(colsum_part, mse_part, loss);
}